// Round 4
// baseline (579.608 us; speedup 1.0000x reference)
//
#include <hip/hip_runtime.h>

#define N_NODES 50000
#define N_EDGES 600000
#define DH 128
#define BN_EPS 1e-5f
#define SCAN_BLOCKS ((N_NODES + 255) / 256)   // 196

typedef __attribute__((ext_vector_type(8))) short bf16x8;
typedef __attribute__((ext_vector_type(4))) float f32x4;

// round-to-nearest-even fp32 -> bf16 (bit trick, sign-safe)
__device__ inline unsigned short f2bf(float x) {
  unsigned u = __float_as_uint(x);
  return (unsigned short)((u + 0x7FFFu + ((u >> 16) & 1u)) >> 16);
}
__device__ inline float bf2f(unsigned short h) {
  return __uint_as_float(((unsigned)h) << 16);
}

// ---------------------------------------------------------------------------
// Pre-split W[K][128] into bf16 hi/lo planes laid out in MFMA B-fragment
// order: plane[((kstep*8 + ctile)*64 + lane)*8 + j]
//   where k = kstep*32 + (lane>>4)*8 + j, n = ctile*16 + (lane&15).
// ---------------------------------------------------------------------------
__global__ __launch_bounds__(256) void convert_W(const float* __restrict__ W,
                                                 unsigned short* __restrict__ hi,
                                                 unsigned short* __restrict__ lo,
                                                 int K) {
  int idx = blockIdx.x * 256 + threadIdx.x;
  if (idx >= K * 128) return;
  int k = idx >> 7;
  int n = idx & 127;
  float x = W[idx];
  unsigned short h = f2bf(x);
  unsigned short l = f2bf(x - bf2f(h));
  int kstep = k >> 5;
  int ctile = n >> 4;
  int lane = ((k >> 3) & 3) * 16 + (n & 15);
  int j = k & 7;
  size_t off = ((size_t)(kstep * 8 + ctile) * 64 + lane) * 8 + j;
  hi[off] = h;
  lo[off] = l;
}

// ---------------------------------------------------------------------------
// Split-bf16 MFMA GEMM, latency-optimized:
//   BM=64 (782 blocks), BN=128. 4 waves/block, wave = 16 rows.
//   A: direct global->register fragments (fp32), converted hi/lo in-reg.
//   B: LDS single-buffer 16 KB, staged from pre-split fragment-order planes.
//   Software prefetch of kstep+1 (A regs + B regs) overlaps the MFMA block.
// ---------------------------------------------------------------------------
template <int K, bool RELU, bool WBF16>
__global__ __launch_bounds__(256) void gemm_mfma(const float* __restrict__ A,
                                                 const unsigned short* __restrict__ Bh,
                                                 const unsigned short* __restrict__ Bl,
                                                 const float* __restrict__ bias,
                                                 float* __restrict__ C,
                                                 unsigned short* __restrict__ Cb,
                                                 int M) {
  constexpr int KSTEPS = K / 32;
  __shared__ __align__(16) unsigned short Bhs[4096];  // 8 KB
  __shared__ __align__(16) unsigned short Bls[4096];  // 8 KB

  const int tid = threadIdx.x;
  const int wave = tid >> 6;
  const int lane = tid & 63;
  const int m0 = blockIdx.x * 64;

  // A fragment source: row = m0 + wave*16 + (lane&15), k-quad = lane>>4
  const int arow = m0 + wave * 16 + (lane & 15);
  const int arow_c = (arow < M) ? arow : (M - 1);   // clamp; tail rows unstored
  const float* aptr = A + (size_t)arow_c * K + ((lane >> 4) * 8);

  // B staging: threads 0-127 stage hi plane (8 KB), 128-255 stage lo plane.
  const unsigned short* bplane = (tid < 128) ? Bh : Bl;
  unsigned short* bdst = (tid < 128) ? Bhs : Bls;
  const int bt = (tid & 127) * 32;  // ushort offset (64 B per thread)

  float4 breg[4];
  float4 areg[2];
  {
    const float4* s = (const float4*)(bplane + bt);
    breg[0] = s[0]; breg[1] = s[1]; breg[2] = s[2]; breg[3] = s[3];
    areg[0] = *(const float4*)(aptr);
    areg[1] = *(const float4*)(aptr + 4);
  }

  f32x4 acc[8];
#pragma unroll
  for (int c = 0; c < 8; ++c) acc[c] = (f32x4){0.f, 0.f, 0.f, 0.f};

  union U8 { bf16x8 v; unsigned short u[8]; };

  for (int ks = 0; ks < KSTEPS; ++ks) {
    // write staged B regs to LDS (prev iter's reads finished at end barrier)
    float4* d = (float4*)(bdst + bt);
    d[0] = breg[0]; d[1] = breg[1]; d[2] = breg[2]; d[3] = breg[3];

    // convert current A regs to bf16 hi/lo fragments (before prefetch clobbers)
    U8 H, L;
    {
      float va[8] = {areg[0].x, areg[0].y, areg[0].z, areg[0].w,
                     areg[1].x, areg[1].y, areg[1].z, areg[1].w};
#pragma unroll
      for (int j = 0; j < 8; ++j) {
        H.u[j] = f2bf(va[j]);
        L.u[j] = f2bf(va[j] - bf2f(H.u[j]));
      }
    }

    // prefetch kstep+1 (in flight across the MFMA block below)
    if (ks + 1 < KSTEPS) {
      const float4* s = (const float4*)(bplane + (size_t)(ks + 1) * 4096 + bt);
      breg[0] = s[0]; breg[1] = s[1]; breg[2] = s[2]; breg[3] = s[3];
      areg[0] = *(const float4*)(aptr + (ks + 1) * 32);
      areg[1] = *(const float4*)(aptr + (ks + 1) * 32 + 4);
    }

    __syncthreads();  // B tile visible

#pragma unroll
    for (int c = 0; c < 8; ++c) {
      bf16x8 bh = *(const bf16x8*)&Bhs[(c * 64 + lane) * 8];
      bf16x8 bl = *(const bf16x8*)&Bls[(c * 64 + lane) * 8];
      acc[c] = __builtin_amdgcn_mfma_f32_16x16x32_bf16(H.v, bh, acc[c], 0, 0, 0);
      acc[c] = __builtin_amdgcn_mfma_f32_16x16x32_bf16(H.v, bl, acc[c], 0, 0, 0);
      acc[c] = __builtin_amdgcn_mfma_f32_16x16x32_bf16(L.v, bh, acc[c], 0, 0, 0);
    }
    __syncthreads();  // all reads done before next iter's LDS write
  }

  // epilogue: C/D layout col=lane&15, row=(lane>>4)*4+reg (16x16 tile)
  const int coln = lane & 15;
  const int rbase = m0 + wave * 16 + (lane >> 4) * 4;
#pragma unroll
  for (int c = 0; c < 8; ++c) {
    float bv = bias[c * 16 + coln];
#pragma unroll
    for (int reg = 0; reg < 4; ++reg) {
      int row = rbase + reg;
      if (row < M) {
        float v = acc[c][reg] + bv;
        if (RELU) v = fmaxf(v, 0.f);
        C[(size_t)row * DH + c * 16 + coln] = v;
        if (WBF16) Cb[(size_t)row * DH + c * 16 + coln] = f2bf(v);
      }
    }
  }
}

// ---------------------------------------------------------------------------
// CSR build: degree histogram -> exclusive scan (3 kernels) -> cursor fill.
// ---------------------------------------------------------------------------
__global__ __launch_bounds__(256) void count_deg(const int* __restrict__ eidx,
                                                 int* __restrict__ cnt) {
  int e = blockIdx.x * 256 + threadIdx.x;
  if (e < N_EDGES) atomicAdd(&cnt[eidx[N_EDGES + e]], 1);
}

__global__ __launch_bounds__(256) void scan_block(const int* __restrict__ cnt,
                                                  int* __restrict__ rs,
                                                  int* __restrict__ partials) {
  int t = threadIdx.x;
  int i = blockIdx.x * 256 + t;
  int v = (i < N_NODES) ? cnt[i] : 0;
  __shared__ int s[256];
  s[t] = v;
  __syncthreads();
#pragma unroll
  for (int off = 1; off < 256; off <<= 1) {
    int add = (t >= off) ? s[t - off] : 0;
    __syncthreads();
    s[t] += add;
    __syncthreads();
  }
  if (i < N_NODES) rs[i] = s[t] - v;
  if (t == 255) partials[blockIdx.x] = s[255];
}

__global__ __launch_bounds__(256) void scan_partials(int* __restrict__ partials) {
  int t = threadIdx.x;
  int v = (t < SCAN_BLOCKS) ? partials[t] : 0;
  __shared__ int s[256];
  s[t] = v;
  __syncthreads();
#pragma unroll
  for (int off = 1; off < 256; off <<= 1) {
    int add = (t >= off) ? s[t - off] : 0;
    __syncthreads();
    s[t] += add;
    __syncthreads();
  }
  if (t < SCAN_BLOCKS) partials[t] = s[t] - v;
}

__global__ __launch_bounds__(256) void add_offsets(int* __restrict__ rs,
                                                   const int* __restrict__ partials) {
  int i = blockIdx.x * 256 + threadIdx.x;
  if (i < N_NODES) rs[i] += partials[blockIdx.x];
  if (i == 0) rs[N_NODES] = N_EDGES;
}

__global__ __launch_bounds__(256) void fill_csr(const int* __restrict__ eidx,
                                                const int* __restrict__ rs,
                                                int* __restrict__ cursor,
                                                int* __restrict__ esrc) {
  int e = blockIdx.x * 256 + threadIdx.x;
  if (e >= N_EDGES) return;
  int d = eidx[N_EDGES + e];
  int p = atomicAdd(&cursor[d], 1);
  esrc[rs[d] + p] = eidx[e];
}

// ---------------------------------------------------------------------------
// Aggregation gather (bf16 neighbors): y[i] = x[i] + sum_j xb[src_j].
// Wave per node; lane handles dims (2*lane, 2*lane+1) via one uint load/edge.
// Self term read exact from fp32 x.
// ---------------------------------------------------------------------------
__global__ __launch_bounds__(256) void gin_aggregate_bf16(
    const unsigned short* __restrict__ xb, const float* __restrict__ x,
    const int* __restrict__ rs, const int* __restrict__ esrc,
    float* __restrict__ y) {
  int node = blockIdx.x * 4 + (threadIdx.x >> 6);
  int lane = threadIdx.x & 63;
  if (node >= N_NODES) return;
  float2 acc = ((const float2*)x)[(size_t)node * 64 + lane];
  const unsigned* xb2 = (const unsigned*)xb;  // 2 bf16 per uint
  int beg = rs[node];
  int end = rs[node + 1];
  int j = beg;
  for (; j + 4 <= end; j += 4) {
    int s0 = esrc[j + 0];
    int s1 = esrc[j + 1];
    int s2 = esrc[j + 2];
    int s3 = esrc[j + 3];
    unsigned v0 = xb2[(size_t)s0 * 64 + lane];
    unsigned v1 = xb2[(size_t)s1 * 64 + lane];
    unsigned v2 = xb2[(size_t)s2 * 64 + lane];
    unsigned v3 = xb2[(size_t)s3 * 64 + lane];
    acc.x += (__uint_as_float(v0 << 16) + __uint_as_float(v1 << 16)) +
             (__uint_as_float(v2 << 16) + __uint_as_float(v3 << 16));
    acc.y += (__uint_as_float(v0 & 0xFFFF0000u) + __uint_as_float(v1 & 0xFFFF0000u)) +
             (__uint_as_float(v2 & 0xFFFF0000u) + __uint_as_float(v3 & 0xFFFF0000u));
  }
  for (; j < end; ++j) {
    unsigned v = xb2[(size_t)esrc[j] * 64 + lane];
    acc.x += __uint_as_float(v << 16);
    acc.y += __uint_as_float(v & 0xFFFF0000u);
  }
  ((float2*)y)[(size_t)node * 64 + lane] = acc;
}

// ---------------------------------------------------------------------------
// Tail: z[i] = dot(x[i,:], tail_W) + tail_b, plus BN batch-stat partials.
// ---------------------------------------------------------------------------
__global__ __launch_bounds__(256) void tail_bn1(const float* __restrict__ x,
                                                const float* __restrict__ tw,
                                                const float* __restrict__ tb,
                                                float* __restrict__ z,
                                                float* __restrict__ red) {
  const int lane = threadIdx.x & 31;
  const int grp = threadIdx.x >> 5;
  float4 w = *(const float4*)(tw + lane * 4);
  float accS = 0.f, accQ = 0.f;
  for (int node = blockIdx.x * 8 + grp; node < N_NODES; node += gridDim.x * 8) {
    float4 v = *(const float4*)(x + (size_t)node * DH + lane * 4);
    float p = v.x * w.x + v.y * w.y + v.z * w.z + v.w * w.w;
#pragma unroll
    for (int m = 16; m; m >>= 1) p += __shfl_xor(p, m, 32);
    if (lane == 0) {
      float zv = p + tb[0];
      z[node] = zv;
      accS += zv;
      accQ += zv * zv;
    }
  }
  __shared__ float sS[256];
  __shared__ float sQ[256];
  sS[threadIdx.x] = accS;
  sQ[threadIdx.x] = accQ;
  __syncthreads();
  for (int s = 128; s; s >>= 1) {
    if (threadIdx.x < s) {
      sS[threadIdx.x] += sS[threadIdx.x + s];
      sQ[threadIdx.x] += sQ[threadIdx.x + s];
    }
    __syncthreads();
  }
  if (threadIdx.x == 0) {
    atomicAdd(&red[0], sS[0]);
    atomicAdd(&red[1], sQ[0]);
  }
}

__global__ __launch_bounds__(256) void bn2(const float* __restrict__ z,
                                           const float* __restrict__ red,
                                           const float* __restrict__ gamma,
                                           const float* __restrict__ beta,
                                           float* __restrict__ out) {
  int i = blockIdx.x * 256 + threadIdx.x;
  if (i >= N_NODES) return;
  float mu = red[0] * (1.0f / N_NODES);
  float var = red[1] * (1.0f / N_NODES) - mu * mu;
  out[i] = (z[i] - mu) * rsqrtf(var + BN_EPS) * gamma[0] + beta[0];
}

// ---------------------------------------------------------------------------
extern "C" void kernel_launch(void* const* d_in, const int* in_sizes, int n_in,
                              void* d_out, int out_size, void* d_ws, size_t ws_size,
                              hipStream_t stream) {
  const float* feature = (const float*)d_in[0];
  const int* eidx = (const int*)d_in[1];
  const float* head_W = (const float*)d_in[2];
  const float* head_b = (const float*)d_in[3];
  const float* gin_W1 = (const float*)d_in[4];
  const float* gin_b1 = (const float*)d_in[5];
  const float* lin_W1 = (const float*)d_in[6];
  const float* lin_b1 = (const float*)d_in[7];
  const float* gin_W2 = (const float*)d_in[8];
  const float* gin_b2 = (const float*)d_in[9];
  const float* lin_W2 = (const float*)d_in[10];
  const float* lin_b2 = (const float*)d_in[11];
  const float* tail_W = (const float*)d_in[12];
  const float* tail_b = (const float*)d_in[13];
  const float* bn_gamma = (const float*)d_in[14];
  const float* bn_beta = (const float*)d_in[15];

  float* A = (float*)d_ws;                       // N x 128
  float* B = A + (size_t)N_NODES * DH;           // N x 128
  float* z = B + (size_t)N_NODES * DH;           // N
  float* red = z + N_NODES;                      // 2 floats
  int* row_start = (int*)(red + 2);              // N+1
  int* cnt = row_start + (N_NODES + 1);          // N
  int* partials = cnt + N_NODES;                 // 256
  int* esrc = partials + 256;                    // E
  unsigned short* wp =
      (unsigned short*)(((uintptr_t)(esrc + N_EDGES) + 15) & ~(uintptr_t)15);
  unsigned short* hH = wp;            // head hi: 512*128
  unsigned short* hL = hH + 65536;    // head lo
  unsigned short* g1H = hL + 65536;   // 128*128 each below
  unsigned short* g1L = g1H + 16384;
  unsigned short* l1H = g1L + 16384;
  unsigned short* l1L = l1H + 16384;
  unsigned short* g2H = l1L + 16384;
  unsigned short* g2L = g2H + 16384;
  unsigned short* l2H = g2L + 16384;
  unsigned short* l2L = l2H + 16384;
  unsigned short* xb = l2L + 16384;   // bf16 mirror, N x 128

  const int gemm_grid = (N_NODES + 63) / 64;     // 782
  const int edge_grid = (N_EDGES + 255) / 256;
  const int agg_grid = (N_NODES + 3) / 4;

  // ---- weight pre-split (tiny) ----
  convert_W<<<(512 * 128 + 255) / 256, 256, 0, stream>>>(head_W, hH, hL, 512);
  convert_W<<<64, 256, 0, stream>>>(gin_W1, g1H, g1L, 128);
  convert_W<<<64, 256, 0, stream>>>(lin_W1, l1H, l1L, 128);
  convert_W<<<64, 256, 0, stream>>>(gin_W2, g2H, g2L, 128);
  convert_W<<<64, 256, 0, stream>>>(lin_W2, l2H, l2L, 128);

  // ---- CSR build (once; reused by both GIN layers) ----
  hipMemsetAsync(cnt, 0, N_NODES * sizeof(int), stream);
  hipMemsetAsync(red, 0, 2 * sizeof(float), stream);
  count_deg<<<edge_grid, 256, 0, stream>>>(eidx, cnt);
  scan_block<<<SCAN_BLOCKS, 256, 0, stream>>>(cnt, row_start, partials);
  scan_partials<<<1, 256, 0, stream>>>(partials);
  add_offsets<<<SCAN_BLOCKS, 256, 0, stream>>>(row_start, partials);
  hipMemsetAsync(cnt, 0, N_NODES * sizeof(int), stream);
  fill_csr<<<edge_grid, 256, 0, stream>>>(eidx, row_start, cnt, esrc);

  // ---- head: A = relu(feature @ head_W + head_b), + bf16 mirror ----
  gemm_mfma<512, true, true><<<gemm_grid, 256, 0, stream>>>(
      feature, hH, hL, head_b, A, xb, N_NODES);

  // ---- layer 1 ----
  gin_aggregate_bf16<<<agg_grid, 256, 0, stream>>>(xb, A, row_start, esrc, B);
  gemm_mfma<128, true, false><<<gemm_grid, 256, 0, stream>>>(
      B, g1H, g1L, gin_b1, A, (unsigned short*)nullptr, N_NODES);
  gemm_mfma<128, false, true><<<gemm_grid, 256, 0, stream>>>(
      A, l1H, l1L, lin_b1, B, xb, N_NODES);

  // ---- layer 2 ----
  gin_aggregate_bf16<<<agg_grid, 256, 0, stream>>>(xb, B, row_start, esrc, A);
  gemm_mfma<128, true, false><<<gemm_grid, 256, 0, stream>>>(
      A, g2H, g2L, gin_b2, B, (unsigned short*)nullptr, N_NODES);
  gemm_mfma<128, false, false><<<gemm_grid, 256, 0, stream>>>(
      B, l2H, l2L, lin_b2, A, (unsigned short*)nullptr, N_NODES);

  // ---- tail + batchnorm ----
  tail_bn1<<<256, 256, 0, stream>>>(A, tail_W, tail_b, z, red);
  bn2<<<(N_NODES + 255) / 256, 256, 0, stream>>>(z, red, bn_gamma, bn_beta, (float*)d_out);
}

// Round 5
// 512.567 us; speedup vs baseline: 1.1308x; 1.1308x over previous
//
#include <hip/hip_runtime.h>

#define N_NODES 50000
#define N_EDGES 600000
#define DH 128
#define BN_EPS 1e-5f
#define SCAN_BLOCKS ((N_NODES + 255) / 256)   // 196

typedef __attribute__((ext_vector_type(8))) short bf16x8;
typedef __attribute__((ext_vector_type(4))) float f32x4;

// round-to-nearest-even fp32 -> bf16 (bit trick, sign-safe)
__device__ inline unsigned short f2bf(float x) {
  unsigned u = __float_as_uint(x);
  return (unsigned short)((u + 0x7FFFu + ((u >> 16) & 1u)) >> 16);
}
__device__ inline float bf2f(unsigned short h) {
  return __uint_as_float(((unsigned)h) << 16);
}

// ---------------------------------------------------------------------------
// Pre-split W[K][128] into bf16 hi/lo planes laid out in MFMA B-fragment
// order: plane[((kstep*8 + ctile)*64 + lane)*8 + j]
//   where k = kstep*32 + (lane>>4)*8 + j, n = ctile*16 + (lane&15).
// ---------------------------------------------------------------------------
__global__ __launch_bounds__(256) void convert_W(const float* __restrict__ W,
                                                 unsigned short* __restrict__ hi,
                                                 unsigned short* __restrict__ lo,
                                                 int K) {
  int idx = blockIdx.x * 256 + threadIdx.x;
  if (idx >= K * 128) return;
  int k = idx >> 7;
  int n = idx & 127;
  float x = W[idx];
  unsigned short h = f2bf(x);
  unsigned short l = f2bf(x - bf2f(h));
  int kstep = k >> 5;
  int ctile = n >> 4;
  int lane = ((k >> 3) & 3) * 16 + (n & 15);
  int j = k & 7;
  size_t off = ((size_t)(kstep * 8 + ctile) * 64 + lane) * 8 + j;
  hi[off] = h;
  lo[off] = l;
}

// ---------------------------------------------------------------------------
// Coalesced fp32 -> bf16 mirror (separate pass; NEVER fuse scattered ushort
// stores into a GEMM epilogue — R4 showed 10x HBM write amplification).
// ---------------------------------------------------------------------------
__global__ __launch_bounds__(256) void to_bf16(const float* __restrict__ x,
                                               unsigned short* __restrict__ xb) {
  int i = blockIdx.x * 256 + threadIdx.x;
  if (i >= N_NODES * DH / 4) return;
  float4 v = ((const float4*)x)[i];
  ushort4 o;
  o.x = f2bf(v.x); o.y = f2bf(v.y); o.z = f2bf(v.z); o.w = f2bf(v.w);
  ((ushort4*)xb)[i] = o;
}

// ---------------------------------------------------------------------------
// Split-bf16 MFMA GEMM: C = act(A @ W + bias), fp32-equivalent precision via
// Ah*Bh + Ah*Bl + Al*Bh. BM=128, BN=128; 4 waves, each 32 rows (2 frag rows).
// A staged fp32->hi/lo into padded LDS; B staged from pre-split planes.
// Register prefetch of kstep+1 issued before the barrier so global latency
// overlaps the 48-MFMA block.
// ---------------------------------------------------------------------------
template <int K, bool RELU>
__global__ __launch_bounds__(256) void gemm_mfma(const float* __restrict__ A,
                                                 const unsigned short* __restrict__ Bh,
                                                 const unsigned short* __restrict__ Bl,
                                                 const float* __restrict__ bias,
                                                 float* __restrict__ C, int M) {
  constexpr int KSTEPS = K / 32;
  constexpr int ASTR = 40;  // padded row stride (u16): 2-way bank alias = free
  __shared__ unsigned short Ah[128 * ASTR];
  __shared__ unsigned short Al[128 * ASTR];
  __shared__ __align__(16) unsigned short Bhs[4096];
  __shared__ __align__(16) unsigned short Bls[4096];

  const int tid = threadIdx.x;
  const int wave = tid >> 6;
  const int lane = tid & 63;
  const int m0 = blockIdx.x * 128;

  // A staging: thread owns row tid>>1, half tid&1 (16 consecutive k's)
  const int s_row = tid >> 1;
  const int s_half = tid & 1;
  const bool s_ok = (m0 + s_row) < M;
  const float* srcA = A + (size_t)(m0 + s_row) * K + s_half * 16;

  float4 abuf[4];
  float4 bbuf[4];  // [0..1] hi plane, [2..3] lo plane
  {
#pragma unroll
    for (int c = 0; c < 4; ++c)
      abuf[c] = s_ok ? *(const float4*)(srcA + c * 4)
                     : make_float4(0.f, 0.f, 0.f, 0.f);
    const float4* sh = (const float4*)Bh;
    const float4* sl = (const float4*)Bl;
    bbuf[0] = sh[tid * 2 + 0];
    bbuf[1] = sh[tid * 2 + 1];
    bbuf[2] = sl[tid * 2 + 0];
    bbuf[3] = sl[tid * 2 + 1];
  }

  f32x4 acc[2][8];
#pragma unroll
  for (int r = 0; r < 2; ++r)
#pragma unroll
    for (int c = 0; c < 8; ++c) acc[r][c] = (f32x4){0.f, 0.f, 0.f, 0.f};

  for (int ks = 0; ks < KSTEPS; ++ks) {
    // ---- write staged regs to LDS (prev MFMA reads done at end barrier) ----
#pragma unroll
    for (int c = 0; c < 4; ++c) {
      float4 v = abuf[c];
      ushort4 h4, l4;
      h4.x = f2bf(v.x); l4.x = f2bf(v.x - bf2f(h4.x));
      h4.y = f2bf(v.y); l4.y = f2bf(v.y - bf2f(h4.y));
      h4.z = f2bf(v.z); l4.z = f2bf(v.z - bf2f(h4.z));
      h4.w = f2bf(v.w); l4.w = f2bf(v.w - bf2f(h4.w));
      int base = s_row * ASTR + s_half * 16 + c * 4;
      *(ushort4*)&Ah[base] = h4;
      *(ushort4*)&Al[base] = l4;
    }
    {
      float4* dh = (float4*)Bhs;
      float4* dl = (float4*)Bls;
      dh[tid * 2 + 0] = bbuf[0];
      dh[tid * 2 + 1] = bbuf[1];
      dl[tid * 2 + 0] = bbuf[2];
      dl[tid * 2 + 1] = bbuf[3];
    }

    // ---- prefetch kstep+1 (overlaps barrier + MFMA block + barrier) ----
    if (ks + 1 < KSTEPS) {
#pragma unroll
      for (int c = 0; c < 4; ++c)
        abuf[c] = s_ok ? *(const float4*)(srcA + (ks + 1) * 32 + c * 4)
                       : make_float4(0.f, 0.f, 0.f, 0.f);
      const float4* sh = (const float4*)(Bh + (size_t)(ks + 1) * 4096);
      const float4* sl = (const float4*)(Bl + (size_t)(ks + 1) * 4096);
      bbuf[0] = sh[tid * 2 + 0];
      bbuf[1] = sh[tid * 2 + 1];
      bbuf[2] = sl[tid * 2 + 0];
      bbuf[3] = sl[tid * 2 + 1];
    }

    __syncthreads();  // LDS tile visible

    bf16x8 afh[2], afl[2];
#pragma unroll
    for (int r = 0; r < 2; ++r) {
      int arow = wave * 32 + r * 16 + (lane & 15);
      int aoff = arow * ASTR + (lane >> 4) * 8;
      afh[r] = *(const bf16x8*)&Ah[aoff];
      afl[r] = *(const bf16x8*)&Al[aoff];
    }
#pragma unroll
    for (int c = 0; c < 8; ++c) {
      bf16x8 bh = *(const bf16x8*)&Bhs[(c * 64 + lane) * 8];
      bf16x8 bl = *(const bf16x8*)&Bls[(c * 64 + lane) * 8];
#pragma unroll
      for (int r = 0; r < 2; ++r) {
        acc[r][c] = __builtin_amdgcn_mfma_f32_16x16x32_bf16(afh[r], bh, acc[r][c], 0, 0, 0);
        acc[r][c] = __builtin_amdgcn_mfma_f32_16x16x32_bf16(afh[r], bl, acc[r][c], 0, 0, 0);
        acc[r][c] = __builtin_amdgcn_mfma_f32_16x16x32_bf16(afl[r], bh, acc[r][c], 0, 0, 0);
      }
    }
    __syncthreads();  // all LDS reads done before next iter's writes
  }

  // ---- epilogue: C/D layout col=lane&15, row=(lane>>4)*4+reg ----
  const int coln = lane & 15;
  const int rown = (lane >> 4) * 4;
#pragma unroll
  for (int c = 0; c < 8; ++c) {
    float bv = bias[c * 16 + coln];
#pragma unroll
    for (int r = 0; r < 2; ++r) {
#pragma unroll
      for (int reg = 0; reg < 4; ++reg) {
        int row = m0 + wave * 32 + r * 16 + rown + reg;
        if (row < M) {
          float v = acc[r][c][reg] + bv;
          if (RELU) v = fmaxf(v, 0.f);
          C[(size_t)row * DH + c * 16 + coln] = v;
        }
      }
    }
  }
}

// ---------------------------------------------------------------------------
// CSR build: degree histogram -> exclusive scan (3 kernels) -> cursor fill.
// ---------------------------------------------------------------------------
__global__ __launch_bounds__(256) void count_deg(const int* __restrict__ eidx,
                                                 int* __restrict__ cnt) {
  int e = blockIdx.x * 256 + threadIdx.x;
  if (e < N_EDGES) atomicAdd(&cnt[eidx[N_EDGES + e]], 1);
}

__global__ __launch_bounds__(256) void scan_block(const int* __restrict__ cnt,
                                                  int* __restrict__ rs,
                                                  int* __restrict__ partials) {
  int t = threadIdx.x;
  int i = blockIdx.x * 256 + t;
  int v = (i < N_NODES) ? cnt[i] : 0;
  __shared__ int s[256];
  s[t] = v;
  __syncthreads();
#pragma unroll
  for (int off = 1; off < 256; off <<= 1) {
    int add = (t >= off) ? s[t - off] : 0;
    __syncthreads();
    s[t] += add;
    __syncthreads();
  }
  if (i < N_NODES) rs[i] = s[t] - v;
  if (t == 255) partials[blockIdx.x] = s[255];
}

__global__ __launch_bounds__(256) void scan_partials(int* __restrict__ partials) {
  int t = threadIdx.x;
  int v = (t < SCAN_BLOCKS) ? partials[t] : 0;
  __shared__ int s[256];
  s[t] = v;
  __syncthreads();
#pragma unroll
  for (int off = 1; off < 256; off <<= 1) {
    int add = (t >= off) ? s[t - off] : 0;
    __syncthreads();
    s[t] += add;
    __syncthreads();
  }
  if (t < SCAN_BLOCKS) partials[t] = s[t] - v;
}

__global__ __launch_bounds__(256) void add_offsets(int* __restrict__ rs,
                                                   const int* __restrict__ partials) {
  int i = blockIdx.x * 256 + threadIdx.x;
  if (i < N_NODES) rs[i] += partials[blockIdx.x];
  if (i == 0) rs[N_NODES] = N_EDGES;
}

__global__ __launch_bounds__(256) void fill_csr(const int* __restrict__ eidx,
                                                const int* __restrict__ rs,
                                                int* __restrict__ cursor,
                                                int* __restrict__ esrc) {
  int e = blockIdx.x * 256 + threadIdx.x;
  if (e >= N_EDGES) return;
  int d = eidx[N_EDGES + e];
  int p = atomicAdd(&cursor[d], 1);
  esrc[rs[d] + p] = eidx[e];
}

// ---------------------------------------------------------------------------
// Aggregation gather (bf16 neighbors): y[i] = x[i] + sum_j xb[src_j].
// Wave per node; lane handles dims (2*lane, 2*lane+1) via one uint load/edge.
// Self term read exact from fp32 x.
// ---------------------------------------------------------------------------
__global__ __launch_bounds__(256) void gin_aggregate_bf16(
    const unsigned short* __restrict__ xb, const float* __restrict__ x,
    const int* __restrict__ rs, const int* __restrict__ esrc,
    float* __restrict__ y) {
  int node = blockIdx.x * 4 + (threadIdx.x >> 6);
  int lane = threadIdx.x & 63;
  if (node >= N_NODES) return;
  float2 acc = ((const float2*)x)[(size_t)node * 64 + lane];
  const unsigned* xb2 = (const unsigned*)xb;  // 2 bf16 per uint
  int beg = rs[node];
  int end = rs[node + 1];
  int j = beg;
  for (; j + 4 <= end; j += 4) {
    int s0 = esrc[j + 0];
    int s1 = esrc[j + 1];
    int s2 = esrc[j + 2];
    int s3 = esrc[j + 3];
    unsigned v0 = xb2[(size_t)s0 * 64 + lane];
    unsigned v1 = xb2[(size_t)s1 * 64 + lane];
    unsigned v2 = xb2[(size_t)s2 * 64 + lane];
    unsigned v3 = xb2[(size_t)s3 * 64 + lane];
    acc.x += (__uint_as_float(v0 << 16) + __uint_as_float(v1 << 16)) +
             (__uint_as_float(v2 << 16) + __uint_as_float(v3 << 16));
    acc.y += (__uint_as_float(v0 & 0xFFFF0000u) + __uint_as_float(v1 & 0xFFFF0000u)) +
             (__uint_as_float(v2 & 0xFFFF0000u) + __uint_as_float(v3 & 0xFFFF0000u));
  }
  for (; j < end; ++j) {
    unsigned v = xb2[(size_t)esrc[j] * 64 + lane];
    acc.x += __uint_as_float(v << 16);
    acc.y += __uint_as_float(v & 0xFFFF0000u);
  }
  ((float2*)y)[(size_t)node * 64 + lane] = acc;
}

// ---------------------------------------------------------------------------
// Tail: z[i] = dot(x[i,:], tail_W) + tail_b, plus BN batch-stat partials.
// ---------------------------------------------------------------------------
__global__ __launch_bounds__(256) void tail_bn1(const float* __restrict__ x,
                                                const float* __restrict__ tw,
                                                const float* __restrict__ tb,
                                                float* __restrict__ z,
                                                float* __restrict__ red) {
  const int lane = threadIdx.x & 31;
  const int grp = threadIdx.x >> 5;
  float4 w = *(const float4*)(tw + lane * 4);
  float accS = 0.f, accQ = 0.f;
  for (int node = blockIdx.x * 8 + grp; node < N_NODES; node += gridDim.x * 8) {
    float4 v = *(const float4*)(x + (size_t)node * DH + lane * 4);
    float p = v.x * w.x + v.y * w.y + v.z * w.z + v.w * w.w;
#pragma unroll
    for (int m = 16; m; m >>= 1) p += __shfl_xor(p, m, 32);
    if (lane == 0) {
      float zv = p + tb[0];
      z[node] = zv;
      accS += zv;
      accQ += zv * zv;
    }
  }
  __shared__ float sS[256];
  __shared__ float sQ[256];
  sS[threadIdx.x] = accS;
  sQ[threadIdx.x] = accQ;
  __syncthreads();
  for (int s = 128; s; s >>= 1) {
    if (threadIdx.x < s) {
      sS[threadIdx.x] += sS[threadIdx.x + s];
      sQ[threadIdx.x] += sQ[threadIdx.x + s];
    }
    __syncthreads();
  }
  if (threadIdx.x == 0) {
    atomicAdd(&red[0], sS[0]);
    atomicAdd(&red[1], sQ[0]);
  }
}

__global__ __launch_bounds__(256) void bn2(const float* __restrict__ z,
                                           const float* __restrict__ red,
                                           const float* __restrict__ gamma,
                                           const float* __restrict__ beta,
                                           float* __restrict__ out) {
  int i = blockIdx.x * 256 + threadIdx.x;
  if (i >= N_NODES) return;
  float mu = red[0] * (1.0f / N_NODES);
  float var = red[1] * (1.0f / N_NODES) - mu * mu;
  out[i] = (z[i] - mu) * rsqrtf(var + BN_EPS) * gamma[0] + beta[0];
}

// ---------------------------------------------------------------------------
extern "C" void kernel_launch(void* const* d_in, const int* in_sizes, int n_in,
                              void* d_out, int out_size, void* d_ws, size_t ws_size,
                              hipStream_t stream) {
  const float* feature = (const float*)d_in[0];
  const int* eidx = (const int*)d_in[1];
  const float* head_W = (const float*)d_in[2];
  const float* head_b = (const float*)d_in[3];
  const float* gin_W1 = (const float*)d_in[4];
  const float* gin_b1 = (const float*)d_in[5];
  const float* lin_W1 = (const float*)d_in[6];
  const float* lin_b1 = (const float*)d_in[7];
  const float* gin_W2 = (const float*)d_in[8];
  const float* gin_b2 = (const float*)d_in[9];
  const float* lin_W2 = (const float*)d_in[10];
  const float* lin_b2 = (const float*)d_in[11];
  const float* tail_W = (const float*)d_in[12];
  const float* tail_b = (const float*)d_in[13];
  const float* bn_gamma = (const float*)d_in[14];
  const float* bn_beta = (const float*)d_in[15];

  float* A = (float*)d_ws;                       // N x 128
  float* B = A + (size_t)N_NODES * DH;           // N x 128
  float* z = B + (size_t)N_NODES * DH;           // N
  float* red = z + N_NODES;                      // 2 floats
  int* row_start = (int*)(red + 2);              // N+1
  int* cnt = row_start + (N_NODES + 1);          // N
  int* partials = cnt + N_NODES;                 // 256
  int* esrc = partials + 256;                    // E
  unsigned short* wp =
      (unsigned short*)(((uintptr_t)(esrc + N_EDGES) + 15) & ~(uintptr_t)15);
  unsigned short* hH = wp;            // head hi: 512*128
  unsigned short* hL = hH + 65536;    // head lo
  unsigned short* g1H = hL + 65536;   // 128*128 each below
  unsigned short* g1L = g1H + 16384;
  unsigned short* l1H = g1L + 16384;
  unsigned short* l1L = l1H + 16384;
  unsigned short* g2H = l1L + 16384;
  unsigned short* g2L = g2H + 16384;
  unsigned short* l2H = g2L + 16384;
  unsigned short* l2L = l2H + 16384;
  unsigned short* xb = l2L + 16384;   // bf16 mirror, N x 128

  const int gemm_grid = (N_NODES + 127) / 128;   // 391
  const int edge_grid = (N_EDGES + 255) / 256;
  const int agg_grid = (N_NODES + 3) / 4;
  const int cvt_grid = (N_NODES * DH / 4 + 255) / 256;

  // ---- weight pre-split (tiny) ----
  convert_W<<<(512 * 128 + 255) / 256, 256, 0, stream>>>(head_W, hH, hL, 512);
  convert_W<<<64, 256, 0, stream>>>(gin_W1, g1H, g1L, 128);
  convert_W<<<64, 256, 0, stream>>>(lin_W1, l1H, l1L, 128);
  convert_W<<<64, 256, 0, stream>>>(gin_W2, g2H, g2L, 128);
  convert_W<<<64, 256, 0, stream>>>(lin_W2, l2H, l2L, 128);

  // ---- CSR build (once; reused by both GIN layers) ----
  hipMemsetAsync(cnt, 0, N_NODES * sizeof(int), stream);
  hipMemsetAsync(red, 0, 2 * sizeof(float), stream);
  count_deg<<<edge_grid, 256, 0, stream>>>(eidx, cnt);
  scan_block<<<SCAN_BLOCKS, 256, 0, stream>>>(cnt, row_start, partials);
  scan_partials<<<1, 256, 0, stream>>>(partials);
  add_offsets<<<SCAN_BLOCKS, 256, 0, stream>>>(row_start, partials);
  hipMemsetAsync(cnt, 0, N_NODES * sizeof(int), stream);
  fill_csr<<<edge_grid, 256, 0, stream>>>(eidx, row_start, cnt, esrc);

  // ---- head: A = relu(feature @ head_W + head_b) ----
  gemm_mfma<512, true><<<gemm_grid, 256, 0, stream>>>(feature, hH, hL, head_b, A, N_NODES);

  // ---- layer 1 ----
  to_bf16<<<cvt_grid, 256, 0, stream>>>(A, xb);
  gin_aggregate_bf16<<<agg_grid, 256, 0, stream>>>(xb, A, row_start, esrc, B);
  gemm_mfma<128, true><<<gemm_grid, 256, 0, stream>>>(B, g1H, g1L, gin_b1, A, N_NODES);
  gemm_mfma<128, false><<<gemm_grid, 256, 0, stream>>>(A, l1H, l1L, lin_b1, B, N_NODES);

  // ---- layer 2 ----
  to_bf16<<<cvt_grid, 256, 0, stream>>>(B, xb);
  gin_aggregate_bf16<<<agg_grid, 256, 0, stream>>>(xb, B, row_start, esrc, A);
  gemm_mfma<128, true><<<gemm_grid, 256, 0, stream>>>(A, g2H, g2L, gin_b2, B, N_NODES);
  gemm_mfma<128, false><<<gemm_grid, 256, 0, stream>>>(B, l2H, l2L, lin_b2, A, N_NODES);

  // ---- tail + batchnorm ----
  tail_bn1<<<256, 256, 0, stream>>>(A, tail_W, tail_b, z, red);
  bn2<<<(N_NODES + 255) / 256, 256, 0, stream>>>(z, red, bn_gamma, bn_beta, (float*)d_out);
}

// Round 6
// 500.140 us; speedup vs baseline: 1.1589x; 1.0248x over previous
//
#include <hip/hip_runtime.h>

#define N_NODES 50000
#define N_EDGES 600000
#define DH 128
#define BN_EPS 1e-5f
#define SCAN_BLOCKS ((N_NODES + 255) / 256)   // 196

typedef __attribute__((ext_vector_type(8))) short bf16x8;
typedef __attribute__((ext_vector_type(4))) float f32x4;

// round-to-nearest-even fp32 -> bf16 (bit trick, sign-safe)
__device__ inline unsigned short f2bf(float x) {
  unsigned u = __float_as_uint(x);
  return (unsigned short)((u + 0x7FFFu + ((u >> 16) & 1u)) >> 16);
}
__device__ inline float bf2f(unsigned short h) {
  return __uint_as_float(((unsigned)h) << 16);
}

// ---------------------------------------------------------------------------
// Pre-split W[K][128] into bf16 hi/lo planes laid out in MFMA B-fragment
// order: plane[((kstep*8 + ctile)*64 + lane)*8 + j]
//   where k = kstep*32 + (lane>>4)*8 + j, n = ctile*16 + (lane&15).
// ---------------------------------------------------------------------------
__global__ __launch_bounds__(256) void convert_W(const float* __restrict__ W,
                                                 unsigned short* __restrict__ hi,
                                                 unsigned short* __restrict__ lo,
                                                 int K) {
  int idx = blockIdx.x * 256 + threadIdx.x;
  if (idx >= K * 128) return;
  int k = idx >> 7;
  int n = idx & 127;
  float x = W[idx];
  unsigned short h = f2bf(x);
  unsigned short l = f2bf(x - bf2f(h));
  int kstep = k >> 5;
  int ctile = n >> 4;
  int lane = ((k >> 3) & 3) * 16 + (n & 15);
  int j = k & 7;
  size_t off = ((size_t)(kstep * 8 + ctile) * 64 + lane) * 8 + j;
  hi[off] = h;
  lo[off] = l;
}

// ---------------------------------------------------------------------------
// Coalesced fp32 -> bf16 mirror (separate pass; NEVER fuse scattered ushort
// stores into a GEMM epilogue — R4 showed 10x HBM write amplification).
// ---------------------------------------------------------------------------
__global__ __launch_bounds__(256) void to_bf16(const float* __restrict__ x,
                                               unsigned short* __restrict__ xb) {
  int i = blockIdx.x * 256 + threadIdx.x;
  if (i >= N_NODES * DH / 4) return;
  float4 v = ((const float4*)x)[i];
  ushort4 o;
  o.x = f2bf(v.x); o.y = f2bf(v.y); o.z = f2bf(v.z); o.w = f2bf(v.w);
  ((ushort4*)xb)[i] = o;
}

// ---------------------------------------------------------------------------
// Barrier-free, LDS-free split-bf16 MFMA GEMM.
// Each wave independently computes a 32-row x 64-col strip of C:
//   A: global -> registers (fp32), split hi/lo in-reg.
//   B: global fragment-ordered pre-split planes, read per c-tile (L2-hot).
// No __shared__, no __syncthreads: waves schedule independently, so TLP
// (12 waves/CU at 782 blocks) hides memory latency without manual prefetch
// registers (which spilled in R5: WRITE_SIZE 25->50 MB).
// ---------------------------------------------------------------------------
template <int K, bool RELU>
__global__ __launch_bounds__(256) void gemm_wave(const float* __restrict__ A,
                                                 const unsigned short* __restrict__ Bh,
                                                 const unsigned short* __restrict__ Bl,
                                                 const float* __restrict__ bias,
                                                 float* __restrict__ C, int M) {
  constexpr int KSTEPS = K / 32;
  const int lane = threadIdx.x & 63;
  const int wgid = blockIdx.x * 4 + (threadIdx.x >> 6);
  const int strip = wgid >> 1;      // 32-row strip
  const int ch = wgid & 1;          // column half (4 c-tiles each)
  if (strip >= (M + 31) / 32) return;

  const int rA = strip * 32 + (lane & 15);
  const int rA0 = (rA < M) ? rA : (M - 1);
  const int rA1 = (rA + 16 < M) ? (rA + 16) : (M - 1);
  const float* ap0 = A + (size_t)rA0 * K + ((lane >> 4) * 8);
  const float* ap1 = A + (size_t)rA1 * K + ((lane >> 4) * 8);

  f32x4 acc[2][4];
#pragma unroll
  for (int r = 0; r < 2; ++r)
#pragma unroll
    for (int c = 0; c < 4; ++c) acc[r][c] = (f32x4){0.f, 0.f, 0.f, 0.f};

  union U8 { bf16x8 v; unsigned short u[8]; };

  for (int ks = 0; ks < KSTEPS; ++ks) {
    float4 a00 = *(const float4*)(ap0 + ks * 32);
    float4 a01 = *(const float4*)(ap0 + ks * 32 + 4);
    float4 a10 = *(const float4*)(ap1 + ks * 32);
    float4 a11 = *(const float4*)(ap1 + ks * 32 + 4);

    U8 H0, L0, H1, L1;
    {
      float v0[8] = {a00.x, a00.y, a00.z, a00.w, a01.x, a01.y, a01.z, a01.w};
      float v1[8] = {a10.x, a10.y, a10.z, a10.w, a11.x, a11.y, a11.z, a11.w};
#pragma unroll
      for (int j = 0; j < 8; ++j) {
        H0.u[j] = f2bf(v0[j]);
        L0.u[j] = f2bf(v0[j] - bf2f(H0.u[j]));
        H1.u[j] = f2bf(v1[j]);
        L1.u[j] = f2bf(v1[j] - bf2f(H1.u[j]));
      }
    }

#pragma unroll
    for (int c = 0; c < 4; ++c) {
      size_t off = (((size_t)ks * 8 + ch * 4 + c) * 64 + lane) * 8;
      bf16x8 bh = *(const bf16x8*)&Bh[off];
      bf16x8 bl = *(const bf16x8*)&Bl[off];
      acc[0][c] = __builtin_amdgcn_mfma_f32_16x16x32_bf16(H0.v, bh, acc[0][c], 0, 0, 0);
      acc[0][c] = __builtin_amdgcn_mfma_f32_16x16x32_bf16(H0.v, bl, acc[0][c], 0, 0, 0);
      acc[0][c] = __builtin_amdgcn_mfma_f32_16x16x32_bf16(L0.v, bh, acc[0][c], 0, 0, 0);
      acc[1][c] = __builtin_amdgcn_mfma_f32_16x16x32_bf16(H1.v, bh, acc[1][c], 0, 0, 0);
      acc[1][c] = __builtin_amdgcn_mfma_f32_16x16x32_bf16(H1.v, bl, acc[1][c], 0, 0, 0);
      acc[1][c] = __builtin_amdgcn_mfma_f32_16x16x32_bf16(L1.v, bh, acc[1][c], 0, 0, 0);
    }
  }

  // epilogue: C/D layout col=lane&15, row=(lane>>4)*4+reg (dword stores only)
  const int coln = lane & 15;
  const int rowoff = (lane >> 4) * 4;
#pragma unroll
  for (int c = 0; c < 4; ++c) {
    int colg = (ch * 4 + c) * 16 + coln;
    float bv = bias[colg];
#pragma unroll
    for (int r = 0; r < 2; ++r) {
#pragma unroll
      for (int reg = 0; reg < 4; ++reg) {
        int row = strip * 32 + r * 16 + rowoff + reg;
        if (row < M) {
          float v = acc[r][c][reg] + bv;
          if (RELU) v = fmaxf(v, 0.f);
          C[(size_t)row * DH + colg] = v;
        }
      }
    }
  }
}

// ---------------------------------------------------------------------------
// CSR build: degree histogram -> exclusive scan (3 kernels) -> cursor fill.
// ---------------------------------------------------------------------------
__global__ __launch_bounds__(256) void count_deg(const int* __restrict__ eidx,
                                                 int* __restrict__ cnt) {
  int e = blockIdx.x * 256 + threadIdx.x;
  if (e < N_EDGES) atomicAdd(&cnt[eidx[N_EDGES + e]], 1);
}

__global__ __launch_bounds__(256) void scan_block(const int* __restrict__ cnt,
                                                  int* __restrict__ rs,
                                                  int* __restrict__ partials) {
  int t = threadIdx.x;
  int i = blockIdx.x * 256 + t;
  int v = (i < N_NODES) ? cnt[i] : 0;
  __shared__ int s[256];
  s[t] = v;
  __syncthreads();
#pragma unroll
  for (int off = 1; off < 256; off <<= 1) {
    int add = (t >= off) ? s[t - off] : 0;
    __syncthreads();
    s[t] += add;
    __syncthreads();
  }
  if (i < N_NODES) rs[i] = s[t] - v;
  if (t == 255) partials[blockIdx.x] = s[255];
}

__global__ __launch_bounds__(256) void scan_partials(int* __restrict__ partials) {
  int t = threadIdx.x;
  int v = (t < SCAN_BLOCKS) ? partials[t] : 0;
  __shared__ int s[256];
  s[t] = v;
  __syncthreads();
#pragma unroll
  for (int off = 1; off < 256; off <<= 1) {
    int add = (t >= off) ? s[t - off] : 0;
    __syncthreads();
    s[t] += add;
    __syncthreads();
  }
  if (t < SCAN_BLOCKS) partials[t] = s[t] - v;
}

__global__ __launch_bounds__(256) void add_offsets(int* __restrict__ rs,
                                                   const int* __restrict__ partials) {
  int i = blockIdx.x * 256 + threadIdx.x;
  if (i < N_NODES) rs[i] += partials[blockIdx.x];
  if (i == 0) rs[N_NODES] = N_EDGES;
}

__global__ __launch_bounds__(256) void fill_csr(const int* __restrict__ eidx,
                                                const int* __restrict__ rs,
                                                int* __restrict__ cursor,
                                                int* __restrict__ esrc) {
  int e = blockIdx.x * 256 + threadIdx.x;
  if (e >= N_EDGES) return;
  int d = eidx[N_EDGES + e];
  int p = atomicAdd(&cursor[d], 1);
  esrc[rs[d] + p] = eidx[e];
}

// ---------------------------------------------------------------------------
// Aggregation gather (bf16 neighbors): y[i] = x[i] + sum_j xb[src_j].
// Wave per node; lane handles dims (2*lane, 2*lane+1) via one uint load/edge.
// Self term read exact from fp32 x.
// ---------------------------------------------------------------------------
__global__ __launch_bounds__(256) void gin_aggregate_bf16(
    const unsigned short* __restrict__ xb, const float* __restrict__ x,
    const int* __restrict__ rs, const int* __restrict__ esrc,
    float* __restrict__ y) {
  int node = blockIdx.x * 4 + (threadIdx.x >> 6);
  int lane = threadIdx.x & 63;
  if (node >= N_NODES) return;
  float2 acc = ((const float2*)x)[(size_t)node * 64 + lane];
  const unsigned* xb2 = (const unsigned*)xb;  // 2 bf16 per uint
  int beg = rs[node];
  int end = rs[node + 1];
  int j = beg;
  for (; j + 4 <= end; j += 4) {
    int s0 = esrc[j + 0];
    int s1 = esrc[j + 1];
    int s2 = esrc[j + 2];
    int s3 = esrc[j + 3];
    unsigned v0 = xb2[(size_t)s0 * 64 + lane];
    unsigned v1 = xb2[(size_t)s1 * 64 + lane];
    unsigned v2 = xb2[(size_t)s2 * 64 + lane];
    unsigned v3 = xb2[(size_t)s3 * 64 + lane];
    acc.x += (__uint_as_float(v0 << 16) + __uint_as_float(v1 << 16)) +
             (__uint_as_float(v2 << 16) + __uint_as_float(v3 << 16));
    acc.y += (__uint_as_float(v0 & 0xFFFF0000u) + __uint_as_float(v1 & 0xFFFF0000u)) +
             (__uint_as_float(v2 & 0xFFFF0000u) + __uint_as_float(v3 & 0xFFFF0000u));
  }
  for (; j < end; ++j) {
    unsigned v = xb2[(size_t)esrc[j] * 64 + lane];
    acc.x += __uint_as_float(v << 16);
    acc.y += __uint_as_float(v & 0xFFFF0000u);
  }
  ((float2*)y)[(size_t)node * 64 + lane] = acc;
}

// ---------------------------------------------------------------------------
// Tail: z[i] = dot(x[i,:], tail_W) + tail_b, plus BN batch-stat partials.
// ---------------------------------------------------------------------------
__global__ __launch_bounds__(256) void tail_bn1(const float* __restrict__ x,
                                                const float* __restrict__ tw,
                                                const float* __restrict__ tb,
                                                float* __restrict__ z,
                                                float* __restrict__ red) {
  const int lane = threadIdx.x & 31;
  const int grp = threadIdx.x >> 5;
  float4 w = *(const float4*)(tw + lane * 4);
  float accS = 0.f, accQ = 0.f;
  for (int node = blockIdx.x * 8 + grp; node < N_NODES; node += gridDim.x * 8) {
    float4 v = *(const float4*)(x + (size_t)node * DH + lane * 4);
    float p = v.x * w.x + v.y * w.y + v.z * w.z + v.w * w.w;
#pragma unroll
    for (int m = 16; m; m >>= 1) p += __shfl_xor(p, m, 32);
    if (lane == 0) {
      float zv = p + tb[0];
      z[node] = zv;
      accS += zv;
      accQ += zv * zv;
    }
  }
  __shared__ float sS[256];
  __shared__ float sQ[256];
  sS[threadIdx.x] = accS;
  sQ[threadIdx.x] = accQ;
  __syncthreads();
  for (int s = 128; s; s >>= 1) {
    if (threadIdx.x < s) {
      sS[threadIdx.x] += sS[threadIdx.x + s];
      sQ[threadIdx.x] += sQ[threadIdx.x + s];
    }
    __syncthreads();
  }
  if (threadIdx.x == 0) {
    atomicAdd(&red[0], sS[0]);
    atomicAdd(&red[1], sQ[0]);
  }
}

__global__ __launch_bounds__(256) void bn2(const float* __restrict__ z,
                                           const float* __restrict__ red,
                                           const float* __restrict__ gamma,
                                           const float* __restrict__ beta,
                                           float* __restrict__ out) {
  int i = blockIdx.x * 256 + threadIdx.x;
  if (i >= N_NODES) return;
  float mu = red[0] * (1.0f / N_NODES);
  float var = red[1] * (1.0f / N_NODES) - mu * mu;
  out[i] = (z[i] - mu) * rsqrtf(var + BN_EPS) * gamma[0] + beta[0];
}

// ---------------------------------------------------------------------------
extern "C" void kernel_launch(void* const* d_in, const int* in_sizes, int n_in,
                              void* d_out, int out_size, void* d_ws, size_t ws_size,
                              hipStream_t stream) {
  const float* feature = (const float*)d_in[0];
  const int* eidx = (const int*)d_in[1];
  const float* head_W = (const float*)d_in[2];
  const float* head_b = (const float*)d_in[3];
  const float* gin_W1 = (const float*)d_in[4];
  const float* gin_b1 = (const float*)d_in[5];
  const float* lin_W1 = (const float*)d_in[6];
  const float* lin_b1 = (const float*)d_in[7];
  const float* gin_W2 = (const float*)d_in[8];
  const float* gin_b2 = (const float*)d_in[9];
  const float* lin_W2 = (const float*)d_in[10];
  const float* lin_b2 = (const float*)d_in[11];
  const float* tail_W = (const float*)d_in[12];
  const float* tail_b = (const float*)d_in[13];
  const float* bn_gamma = (const float*)d_in[14];
  const float* bn_beta = (const float*)d_in[15];

  float* A = (float*)d_ws;                       // N x 128
  float* B = A + (size_t)N_NODES * DH;           // N x 128
  float* z = B + (size_t)N_NODES * DH;           // N
  float* red = z + N_NODES;                      // 2 floats
  int* row_start = (int*)(red + 2);              // N+1
  int* cnt = row_start + (N_NODES + 1);          // N
  int* partials = cnt + N_NODES;                 // 256
  int* esrc = partials + 256;                    // E
  unsigned short* wp =
      (unsigned short*)(((uintptr_t)(esrc + N_EDGES) + 15) & ~(uintptr_t)15);
  unsigned short* hH = wp;            // head hi: 512*128
  unsigned short* hL = hH + 65536;    // head lo
  unsigned short* g1H = hL + 65536;   // 128*128 each below
  unsigned short* g1L = g1H + 16384;
  unsigned short* l1H = g1L + 16384;
  unsigned short* l1L = l1H + 16384;
  unsigned short* g2H = l1L + 16384;
  unsigned short* g2L = g2H + 16384;
  unsigned short* l2H = g2L + 16384;
  unsigned short* l2L = l2H + 16384;
  unsigned short* xb = l2L + 16384;   // bf16 mirror, N x 128

  // waves = 2 * ceil(N/32); 4 waves per 256-thr block
  const int gemm_grid = ((2 * ((N_NODES + 31) / 32)) + 3) / 4;  // 782
  const int edge_grid = (N_EDGES + 255) / 256;
  const int agg_grid = (N_NODES + 3) / 4;
  const int cvt_grid = (N_NODES * DH / 4 + 255) / 256;

  // ---- weight pre-split (tiny) ----
  convert_W<<<(512 * 128 + 255) / 256, 256, 0, stream>>>(head_W, hH, hL, 512);
  convert_W<<<64, 256, 0, stream>>>(gin_W1, g1H, g1L, 128);
  convert_W<<<64, 256, 0, stream>>>(lin_W1, l1H, l1L, 128);
  convert_W<<<64, 256, 0, stream>>>(gin_W2, g2H, g2L, 128);
  convert_W<<<64, 256, 0, stream>>>(lin_W2, l2H, l2L, 128);

  // ---- CSR build (once; reused by both GIN layers) ----
  hipMemsetAsync(cnt, 0, N_NODES * sizeof(int), stream);
  hipMemsetAsync(red, 0, 2 * sizeof(float), stream);
  count_deg<<<edge_grid, 256, 0, stream>>>(eidx, cnt);
  scan_block<<<SCAN_BLOCKS, 256, 0, stream>>>(cnt, row_start, partials);
  scan_partials<<<1, 256, 0, stream>>>(partials);
  add_offsets<<<SCAN_BLOCKS, 256, 0, stream>>>(row_start, partials);
  hipMemsetAsync(cnt, 0, N_NODES * sizeof(int), stream);
  fill_csr<<<edge_grid, 256, 0, stream>>>(eidx, row_start, cnt, esrc);

  // ---- head: A = relu(feature @ head_W + head_b) ----
  gemm_wave<512, true><<<gemm_grid, 256, 0, stream>>>(feature, hH, hL, head_b, A, N_NODES);

  // ---- layer 1 ----
  to_bf16<<<cvt_grid, 256, 0, stream>>>(A, xb);
  gin_aggregate_bf16<<<agg_grid, 256, 0, stream>>>(xb, A, row_start, esrc, B);
  gemm_wave<128, true><<<gemm_grid, 256, 0, stream>>>(B, g1H, g1L, gin_b1, A, N_NODES);
  gemm_wave<128, false><<<gemm_grid, 256, 0, stream>>>(A, l1H, l1L, lin_b1, B, N_NODES);

  // ---- layer 2 ----
  to_bf16<<<cvt_grid, 256, 0, stream>>>(B, xb);
  gin_aggregate_bf16<<<agg_grid, 256, 0, stream>>>(xb, B, row_start, esrc, A);
  gemm_wave<128, true><<<gemm_grid, 256, 0, stream>>>(A, g2H, g2L, gin_b2, B, N_NODES);
  gemm_wave<128, false><<<gemm_grid, 256, 0, stream>>>(B, l2H, l2L, lin_b2, A, N_NODES);

  // ---- tail + batchnorm ----
  tail_bn1<<<256, 256, 0, stream>>>(A, tail_W, tail_b, z, red);
  bn2<<<(N_NODES + 255) / 256, 256, 0, stream>>>(z, red, bn_gamma, bn_beta, (float*)d_out);
}

// Round 7
// 470.090 us; speedup vs baseline: 1.2330x; 1.0639x over previous
//
#include <hip/hip_runtime.h>

#define N_NODES 50000
#define N_EDGES 600000
#define DH 128
#define BN_EPS 1e-5f
#define SCAN_BLOCKS ((N_NODES + 255) / 256)   // 196

typedef __attribute__((ext_vector_type(8))) short bf16x8;
typedef __attribute__((ext_vector_type(4))) float f32x4;

// round-to-nearest-even fp32 -> bf16 (bit trick, sign-safe)
__device__ inline unsigned short f2bf(float x) {
  unsigned u = __float_as_uint(x);
  return (unsigned short)((u + 0x7FFFu + ((u >> 16) & 1u)) >> 16);
}
__device__ inline float bf2f(unsigned short h) {
  return __uint_as_float(((unsigned)h) << 16);
}

// ---------------------------------------------------------------------------
// Pre-split W[K][128] into bf16 hi/lo planes laid out in MFMA B-fragment
// order: plane[((kstep*8 + ctile)*64 + lane)*8 + j]
//   where k = kstep*32 + (lane>>4)*8 + j, n = ctile*16 + (lane&15).
// W kept split (Wh+Wl == W to 2^-17) so GEMM error is A's bf16 rounding only.
// ---------------------------------------------------------------------------
__global__ __launch_bounds__(256) void convert_W(const float* __restrict__ W,
                                                 unsigned short* __restrict__ hi,
                                                 unsigned short* __restrict__ lo,
                                                 int K) {
  int idx = blockIdx.x * 256 + threadIdx.x;
  if (idx >= K * 128) return;
  int k = idx >> 7;
  int n = idx & 127;
  float x = W[idx];
  unsigned short h = f2bf(x);
  unsigned short l = f2bf(x - bf2f(h));
  int kstep = k >> 5;
  int ctile = n >> 4;
  int lane = ((k >> 3) & 3) * 16 + (n & 15);
  int j = k & 7;
  size_t off = ((size_t)(kstep * 8 + ctile) * 64 + lane) * 8 + j;
  hi[off] = h;
  lo[off] = l;
}

// ---------------------------------------------------------------------------
// Coalesced fp32 -> bf16 mirror (separate pass; NEVER fuse scattered ushort
// stores into a GEMM epilogue — R4 showed 10x HBM write amplification).
// ---------------------------------------------------------------------------
__global__ __launch_bounds__(256) void to_bf16(const float* __restrict__ x,
                                               unsigned short* __restrict__ xb) {
  int i = blockIdx.x * 256 + threadIdx.x;
  if (i >= N_NODES * DH / 4) return;
  float4 v = ((const float4*)x)[i];
  ushort4 o;
  o.x = f2bf(v.x); o.y = f2bf(v.y); o.z = f2bf(v.z); o.w = f2bf(v.w);
  ((ushort4*)xb)[i] = o;
}

// ---------------------------------------------------------------------------
// Barrier-free, LDS-free MFMA GEMM. A in bf16 (direct load if ABF16, else
// fp32 load + cheap 3-op/elem in-reg cvt), W split hi/lo (2 MFMA per tile ->
// GEMM error = A rounding only, ~2e-3 rel).
// Each wave owns a 32-row x 64-col strip; unroll 2 for load ILP.
// ---------------------------------------------------------------------------
template <int K, bool RELU, bool ABF16>
__global__ __launch_bounds__(256) void gemm_wave(const void* __restrict__ Av,
                                                 const unsigned short* __restrict__ Bh,
                                                 const unsigned short* __restrict__ Bl,
                                                 const float* __restrict__ bias,
                                                 float* __restrict__ C, int M) {
  constexpr int KSTEPS = K / 32;
  const int lane = threadIdx.x & 63;
  const int wgid = blockIdx.x * 4 + (threadIdx.x >> 6);
  const int strip = wgid >> 1;      // 32-row strip
  const int ch = wgid & 1;          // column half (4 c-tiles each)
  if (strip >= (M + 31) / 32) return;

  const int rA = strip * 32 + (lane & 15);
  const int rA0 = (rA < M) ? rA : (M - 1);
  const int rA1 = (rA + 16 < M) ? (rA + 16) : (M - 1);

  const float* ap0f = nullptr;
  const float* ap1f = nullptr;
  const unsigned short* ap0b = nullptr;
  const unsigned short* ap1b = nullptr;
  if (ABF16) {
    const unsigned short* ab = (const unsigned short*)Av;
    ap0b = ab + (size_t)rA0 * K + ((lane >> 4) * 8);
    ap1b = ab + (size_t)rA1 * K + ((lane >> 4) * 8);
  } else {
    const float* af = (const float*)Av;
    ap0f = af + (size_t)rA0 * K + ((lane >> 4) * 8);
    ap1f = af + (size_t)rA1 * K + ((lane >> 4) * 8);
  }

  f32x4 acc[2][4];
#pragma unroll
  for (int r = 0; r < 2; ++r)
#pragma unroll
    for (int c = 0; c < 4; ++c) acc[r][c] = (f32x4){0.f, 0.f, 0.f, 0.f};

  union U8 { bf16x8 v; unsigned short u[8]; };

#pragma unroll 2
  for (int ks = 0; ks < KSTEPS; ++ks) {
    bf16x8 a0, a1;
    if (ABF16) {
      a0 = *(const bf16x8*)(ap0b + ks * 32);
      a1 = *(const bf16x8*)(ap1b + ks * 32);
    } else {
      float4 f00 = *(const float4*)(ap0f + ks * 32);
      float4 f01 = *(const float4*)(ap0f + ks * 32 + 4);
      float4 f10 = *(const float4*)(ap1f + ks * 32);
      float4 f11 = *(const float4*)(ap1f + ks * 32 + 4);
      U8 A0, A1;
      float v0[8] = {f00.x, f00.y, f00.z, f00.w, f01.x, f01.y, f01.z, f01.w};
      float v1[8] = {f10.x, f10.y, f10.z, f10.w, f11.x, f11.y, f11.z, f11.w};
#pragma unroll
      for (int j = 0; j < 8; ++j) {
        A0.u[j] = f2bf(v0[j]);
        A1.u[j] = f2bf(v1[j]);
      }
      a0 = A0.v;
      a1 = A1.v;
    }

#pragma unroll
    for (int c = 0; c < 4; ++c) {
      size_t off = (((size_t)ks * 8 + ch * 4 + c) * 64 + lane) * 8;
      bf16x8 bh = *(const bf16x8*)&Bh[off];
      bf16x8 bl = *(const bf16x8*)&Bl[off];
      acc[0][c] = __builtin_amdgcn_mfma_f32_16x16x32_bf16(a0, bh, acc[0][c], 0, 0, 0);
      acc[0][c] = __builtin_amdgcn_mfma_f32_16x16x32_bf16(a0, bl, acc[0][c], 0, 0, 0);
      acc[1][c] = __builtin_amdgcn_mfma_f32_16x16x32_bf16(a1, bh, acc[1][c], 0, 0, 0);
      acc[1][c] = __builtin_amdgcn_mfma_f32_16x16x32_bf16(a1, bl, acc[1][c], 0, 0, 0);
    }
  }

  // epilogue: C/D layout col=lane&15, row=(lane>>4)*4+reg (dword stores only)
  const int coln = lane & 15;
  const int rowoff = (lane >> 4) * 4;
#pragma unroll
  for (int c = 0; c < 4; ++c) {
    int colg = (ch * 4 + c) * 16 + coln;
    float bv = bias[colg];
#pragma unroll
    for (int r = 0; r < 2; ++r) {
#pragma unroll
      for (int reg = 0; reg < 4; ++reg) {
        int row = strip * 32 + r * 16 + rowoff + reg;
        if (row < M) {
          float v = acc[r][c][reg] + bv;
          if (RELU) v = fmaxf(v, 0.f);
          C[(size_t)row * DH + colg] = v;
        }
      }
    }
  }
}

// ---------------------------------------------------------------------------
// CSR build: degree histogram -> exclusive scan (3 kernels) -> cursor fill.
// ---------------------------------------------------------------------------
__global__ __launch_bounds__(256) void count_deg(const int* __restrict__ eidx,
                                                 int* __restrict__ cnt) {
  int e = blockIdx.x * 256 + threadIdx.x;
  if (e < N_EDGES) atomicAdd(&cnt[eidx[N_EDGES + e]], 1);
}

__global__ __launch_bounds__(256) void scan_block(const int* __restrict__ cnt,
                                                  int* __restrict__ rs,
                                                  int* __restrict__ partials) {
  int t = threadIdx.x;
  int i = blockIdx.x * 256 + t;
  int v = (i < N_NODES) ? cnt[i] : 0;
  __shared__ int s[256];
  s[t] = v;
  __syncthreads();
#pragma unroll
  for (int off = 1; off < 256; off <<= 1) {
    int add = (t >= off) ? s[t - off] : 0;
    __syncthreads();
    s[t] += add;
    __syncthreads();
  }
  if (i < N_NODES) rs[i] = s[t] - v;
  if (t == 255) partials[blockIdx.x] = s[255];
}

__global__ __launch_bounds__(256) void scan_partials(int* __restrict__ partials) {
  int t = threadIdx.x;
  int v = (t < SCAN_BLOCKS) ? partials[t] : 0;
  __shared__ int s[256];
  s[t] = v;
  __syncthreads();
#pragma unroll
  for (int off = 1; off < 256; off <<= 1) {
    int add = (t >= off) ? s[t - off] : 0;
    __syncthreads();
    s[t] += add;
    __syncthreads();
  }
  if (t < SCAN_BLOCKS) partials[t] = s[t] - v;
}

__global__ __launch_bounds__(256) void add_offsets(int* __restrict__ rs,
                                                   const int* __restrict__ partials) {
  int i = blockIdx.x * 256 + threadIdx.x;
  if (i < N_NODES) rs[i] += partials[blockIdx.x];
  if (i == 0) rs[N_NODES] = N_EDGES;
}

__global__ __launch_bounds__(256) void fill_csr(const int* __restrict__ eidx,
                                                const int* __restrict__ rs,
                                                int* __restrict__ cursor,
                                                int* __restrict__ esrc) {
  int e = blockIdx.x * 256 + threadIdx.x;
  if (e >= N_EDGES) return;
  int d = eidx[N_EDGES + e];
  int p = atomicAdd(&cursor[d], 1);
  esrc[rs[d] + p] = eidx[e];
}

// ---------------------------------------------------------------------------
// Aggregation gather (bf16 neighbors): yb[i] = bf16(x[i] + sum_j xb[src_j]).
// Wave per node; lane handles dims (2*lane, 2*lane+1) via one uint load/edge.
// Self term read exact from fp32 x. Output written bf16-packed (coalesced
// uint per lane) and consumed directly as MFMA A operand by the gin GEMM.
// ---------------------------------------------------------------------------
__global__ __launch_bounds__(256) void gin_aggregate_bf16(
    const unsigned short* __restrict__ xb, const float* __restrict__ x,
    const int* __restrict__ rs, const int* __restrict__ esrc,
    unsigned* __restrict__ yb) {
  int node = blockIdx.x * 4 + (threadIdx.x >> 6);
  int lane = threadIdx.x & 63;
  if (node >= N_NODES) return;
  float2 acc = ((const float2*)x)[(size_t)node * 64 + lane];
  const unsigned* xb2 = (const unsigned*)xb;  // 2 bf16 per uint
  int beg = rs[node];
  int end = rs[node + 1];
  int j = beg;
  for (; j + 4 <= end; j += 4) {
    int s0 = esrc[j + 0];
    int s1 = esrc[j + 1];
    int s2 = esrc[j + 2];
    int s3 = esrc[j + 3];
    unsigned v0 = xb2[(size_t)s0 * 64 + lane];
    unsigned v1 = xb2[(size_t)s1 * 64 + lane];
    unsigned v2 = xb2[(size_t)s2 * 64 + lane];
    unsigned v3 = xb2[(size_t)s3 * 64 + lane];
    acc.x += (__uint_as_float(v0 << 16) + __uint_as_float(v1 << 16)) +
             (__uint_as_float(v2 << 16) + __uint_as_float(v3 << 16));
    acc.y += (__uint_as_float(v0 & 0xFFFF0000u) + __uint_as_float(v1 & 0xFFFF0000u)) +
             (__uint_as_float(v2 & 0xFFFF0000u) + __uint_as_float(v3 & 0xFFFF0000u));
  }
  for (; j < end; ++j) {
    unsigned v = xb2[(size_t)esrc[j] * 64 + lane];
    acc.x += __uint_as_float(v << 16);
    acc.y += __uint_as_float(v & 0xFFFF0000u);
  }
  yb[(size_t)node * 64 + lane] =
      (unsigned)f2bf(acc.x) | ((unsigned)f2bf(acc.y) << 16);
}

// ---------------------------------------------------------------------------
// Tail: z[i] = dot(x[i,:], tail_W) + tail_b, plus BN batch-stat partials.
// ---------------------------------------------------------------------------
__global__ __launch_bounds__(256) void tail_bn1(const float* __restrict__ x,
                                                const float* __restrict__ tw,
                                                const float* __restrict__ tb,
                                                float* __restrict__ z,
                                                float* __restrict__ red) {
  const int lane = threadIdx.x & 31;
  const int grp = threadIdx.x >> 5;
  float4 w = *(const float4*)(tw + lane * 4);
  float accS = 0.f, accQ = 0.f;
  for (int node = blockIdx.x * 8 + grp; node < N_NODES; node += gridDim.x * 8) {
    float4 v = *(const float4*)(x + (size_t)node * DH + lane * 4);
    float p = v.x * w.x + v.y * w.y + v.z * w.z + v.w * w.w;
#pragma unroll
    for (int m = 16; m; m >>= 1) p += __shfl_xor(p, m, 32);
    if (lane == 0) {
      float zv = p + tb[0];
      z[node] = zv;
      accS += zv;
      accQ += zv * zv;
    }
  }
  __shared__ float sS[256];
  __shared__ float sQ[256];
  sS[threadIdx.x] = accS;
  sQ[threadIdx.x] = accQ;
  __syncthreads();
  for (int s = 128; s; s >>= 1) {
    if (threadIdx.x < s) {
      sS[threadIdx.x] += sS[threadIdx.x + s];
      sQ[threadIdx.x] += sQ[threadIdx.x + s];
    }
    __syncthreads();
  }
  if (threadIdx.x == 0) {
    atomicAdd(&red[0], sS[0]);
    atomicAdd(&red[1], sQ[0]);
  }
}

__global__ __launch_bounds__(256) void bn2(const float* __restrict__ z,
                                           const float* __restrict__ red,
                                           const float* __restrict__ gamma,
                                           const float* __restrict__ beta,
                                           float* __restrict__ out) {
  int i = blockIdx.x * 256 + threadIdx.x;
  if (i >= N_NODES) return;
  float mu = red[0] * (1.0f / N_NODES);
  float var = red[1] * (1.0f / N_NODES) - mu * mu;
  out[i] = (z[i] - mu) * rsqrtf(var + BN_EPS) * gamma[0] + beta[0];
}

// ---------------------------------------------------------------------------
extern "C" void kernel_launch(void* const* d_in, const int* in_sizes, int n_in,
                              void* d_out, int out_size, void* d_ws, size_t ws_size,
                              hipStream_t stream) {
  const float* feature = (const float*)d_in[0];
  const int* eidx = (const int*)d_in[1];
  const float* head_W = (const float*)d_in[2];
  const float* head_b = (const float*)d_in[3];
  const float* gin_W1 = (const float*)d_in[4];
  const float* gin_b1 = (const float*)d_in[5];
  const float* lin_W1 = (const float*)d_in[6];
  const float* lin_b1 = (const float*)d_in[7];
  const float* gin_W2 = (const float*)d_in[8];
  const float* gin_b2 = (const float*)d_in[9];
  const float* lin_W2 = (const float*)d_in[10];
  const float* lin_b2 = (const float*)d_in[11];
  const float* tail_W = (const float*)d_in[12];
  const float* tail_b = (const float*)d_in[13];
  const float* bn_gamma = (const float*)d_in[14];
  const float* bn_beta = (const float*)d_in[15];

  float* X = (float*)d_ws;                       // N x 128 fp32
  float* H = X + (size_t)N_NODES * DH;           // N x 128 fp32
  float* z = H + (size_t)N_NODES * DH;           // N
  float* red = z + N_NODES;                      // 2 floats
  int* row_start = (int*)(red + 2);              // N+1
  int* cnt = row_start + (N_NODES + 1);          // N
  int* partials = cnt + N_NODES;                 // 256
  int* esrc = partials + 256;                    // E
  unsigned short* wp =
      (unsigned short*)(((uintptr_t)(esrc + N_EDGES) + 15) & ~(uintptr_t)15);
  unsigned short* hH = wp;            // head hi: 512*128
  unsigned short* hL = hH + 65536;    // head lo
  unsigned short* g1H = hL + 65536;   // 128*128 each below
  unsigned short* g1L = g1H + 16384;
  unsigned short* l1H = g1L + 16384;
  unsigned short* l1L = l1H + 16384;
  unsigned short* g2H = l1L + 16384;
  unsigned short* g2L = g2H + 16384;
  unsigned short* l2H = g2L + 16384;
  unsigned short* l2L = l2H + 16384;
  unsigned short* xb = l2L + 16384;              // bf16 mirror, N x 128
  unsigned* yb = (unsigned*)(xb + (size_t)N_NODES * DH);  // agg out bf16 N x 128

  // waves = 2 * ceil(N/32); 4 waves per 256-thr block
  const int gemm_grid = ((2 * ((N_NODES + 31) / 32)) + 3) / 4;  // 782
  const int edge_grid = (N_EDGES + 255) / 256;
  const int agg_grid = (N_NODES + 3) / 4;
  const int cvt_grid = (N_NODES * DH / 4 + 255) / 256;

  // ---- weight pre-split (tiny) ----
  convert_W<<<(512 * 128 + 255) / 256, 256, 0, stream>>>(head_W, hH, hL, 512);
  convert_W<<<64, 256, 0, stream>>>(gin_W1, g1H, g1L, 128);
  convert_W<<<64, 256, 0, stream>>>(lin_W1, l1H, l1L, 128);
  convert_W<<<64, 256, 0, stream>>>(gin_W2, g2H, g2L, 128);
  convert_W<<<64, 256, 0, stream>>>(lin_W2, l2H, l2L, 128);

  // ---- CSR build (once; reused by both GIN layers) ----
  hipMemsetAsync(cnt, 0, N_NODES * sizeof(int), stream);
  hipMemsetAsync(red, 0, 2 * sizeof(float), stream);
  count_deg<<<edge_grid, 256, 0, stream>>>(eidx, cnt);
  scan_block<<<SCAN_BLOCKS, 256, 0, stream>>>(cnt, row_start, partials);
  scan_partials<<<1, 256, 0, stream>>>(partials);
  add_offsets<<<SCAN_BLOCKS, 256, 0, stream>>>(row_start, partials);
  hipMemsetAsync(cnt, 0, N_NODES * sizeof(int), stream);
  fill_csr<<<edge_grid, 256, 0, stream>>>(eidx, row_start, cnt, esrc);

  // ---- head: X = relu(feature @ head_W + head_b) ----
  gemm_wave<512, true, false><<<gemm_grid, 256, 0, stream>>>(
      feature, hH, hL, head_b, X, N_NODES);

  // ---- layer 1 ----
  to_bf16<<<cvt_grid, 256, 0, stream>>>(X, xb);
  gin_aggregate_bf16<<<agg_grid, 256, 0, stream>>>(xb, X, row_start, esrc, yb);
  gemm_wave<128, true, true><<<gemm_grid, 256, 0, stream>>>(
      yb, g1H, g1L, gin_b1, H, N_NODES);
  gemm_wave<128, false, false><<<gemm_grid, 256, 0, stream>>>(
      H, l1H, l1L, lin_b1, X, N_NODES);

  // ---- layer 2 ----
  to_bf16<<<cvt_grid, 256, 0, stream>>>(X, xb);
  gin_aggregate_bf16<<<agg_grid, 256, 0, stream>>>(xb, X, row_start, esrc, yb);
  gemm_wave<128, true, true><<<gemm_grid, 256, 0, stream>>>(
      yb, g2H, g2L, gin_b2, H, N_NODES);
  gemm_wave<128, false, false><<<gemm_grid, 256, 0, stream>>>(
      H, l2H, l2L, lin_b2, X, N_NODES);

  // ---- tail + batchnorm ----
  tail_bn1<<<256, 256, 0, stream>>>(X, tail_W, tail_b, z, red);
  bn2<<<(N_NODES + 255) / 256, 256, 0, stream>>>(z, red, bn_gamma, bn_beta, (float*)d_out);
}

// Round 8
// 450.156 us; speedup vs baseline: 1.2876x; 1.0443x over previous
//
#include <hip/hip_runtime.h>

#define N_NODES 50000
#define N_EDGES 600000
#define DH 128
#define BN_EPS 1e-5f
#define SCAN_BLOCKS ((N_NODES + 255) / 256)   // 196

typedef __attribute__((ext_vector_type(8))) short bf16x8;
typedef __attribute__((ext_vector_type(4))) float f32x4;

// round-to-nearest-even fp32 -> bf16 (bit trick, sign-safe)
__device__ inline unsigned short f2bf(float x) {
  unsigned u = __float_as_uint(x);
  return (unsigned short)((u + 0x7FFFu + ((u >> 16) & 1u)) >> 16);
}
__device__ inline float bf2f(unsigned short h) {
  return __uint_as_float(((unsigned)h) << 16);
}

// async global->LDS, 16 B per lane: lane i's data lands at lds_base + i*16.
// lds_base must be wave-uniform; global ptr is per-lane.
__device__ inline void gl_lds16(const unsigned short* g, unsigned short* l) {
  __builtin_amdgcn_global_load_lds(
      (const __attribute__((address_space(1))) unsigned int*)g,
      (__attribute__((address_space(3))) unsigned int*)l, 16, 0, 0);
}

// ---------------------------------------------------------------------------
// Pre-split W[K][128] into bf16 hi/lo planes laid out in MFMA B-fragment
// order: plane[((kstep*8 + ctile)*64 + lane)*8 + j]
//   where k = kstep*32 + (lane>>4)*8 + j, n = ctile*16 + (lane&15).
// W kept split (Wh+Wl == W to 2^-17) so GEMM error is A's bf16 rounding only.
// ---------------------------------------------------------------------------
__global__ __launch_bounds__(256) void convert_W(const float* __restrict__ W,
                                                 unsigned short* __restrict__ hi,
                                                 unsigned short* __restrict__ lo,
                                                 int K) {
  int idx = blockIdx.x * 256 + threadIdx.x;
  if (idx >= K * 128) return;
  int k = idx >> 7;
  int n = idx & 127;
  float x = W[idx];
  unsigned short h = f2bf(x);
  unsigned short l = f2bf(x - bf2f(h));
  int kstep = k >> 5;
  int ctile = n >> 4;
  int lane = ((k >> 3) & 3) * 16 + (n & 15);
  int j = k & 7;
  size_t off = ((size_t)(kstep * 8 + ctile) * 64 + lane) * 8 + j;
  hi[off] = h;
  lo[off] = l;
}

// ---------------------------------------------------------------------------
// Coalesced fp32 -> bf16 mirror (separate pass; NEVER fuse scattered ushort
// stores into a GEMM epilogue — R4 showed 10x HBM write amplification).
// ---------------------------------------------------------------------------
__global__ __launch_bounds__(256) void to_bf16(const float* __restrict__ x,
                                               unsigned short* __restrict__ xb) {
  int i = blockIdx.x * 256 + threadIdx.x;
  if (i >= N_NODES * DH / 4) return;
  float4 v = ((const float4*)x)[i];
  ushort4 o;
  o.x = f2bf(v.x); o.y = f2bf(v.y); o.z = f2bf(v.z); o.w = f2bf(v.w);
  ((ushort4*)xb)[i] = o;
}

// ---------------------------------------------------------------------------
// m97-style LDS-staged MFMA GEMM: C[M,128] = act(A @ W + bias).
// BM=64 (grid 782 -> ~3 blocks/CU co-resident to cover barrier drains),
// BN=128, BK=32, 4 waves; wave = 32 rows x 64 cols (2 A-frags + 8 B-frags
// per kstep -> 10 ds_read_b128 : 16 MFMA, LDS/MFMA balanced).
// A staged cooperatively (fp32 -> bf16 RNE in-stage, or raw bf16 16B copies),
// padded stride 40 u16 (2-way bank alias = free).
// B staged via global_load_lds width=16 (flat copy of fragment-ordered
// pre-split planes; no VGPR round trip).
// ---------------------------------------------------------------------------
template <int K, bool RELU, bool ABF16>
__global__ __launch_bounds__(256) void gemm_tile(const void* __restrict__ Av,
                                                 const unsigned short* __restrict__ Bh,
                                                 const unsigned short* __restrict__ Bl,
                                                 const float* __restrict__ bias,
                                                 float* __restrict__ C, int M) {
  constexpr int KSTEPS = K / 32;
  constexpr int ASTR = 40;
  __shared__ __align__(16) unsigned short Ah[64 * ASTR];   // 5 KB
  __shared__ __align__(16) unsigned short Bhs[4096];       // 8 KB
  __shared__ __align__(16) unsigned short Bls[4096];       // 8 KB

  const int tid = threadIdx.x;
  const int wave = tid >> 6;
  const int lane = tid & 63;
  const int m0 = blockIdx.x * 64;

  // A staging: thread owns row tid>>2 (0..63), k-oct tid&3 (8 elems)
  const int s_row = tid >> 2;
  const int s_oct = tid & 3;
  const int g_row = m0 + s_row;
  const int g_rowc = (g_row < M) ? g_row : (M - 1);  // clamp; tail unstored
  const float* af = nullptr;
  const unsigned short* ab = nullptr;
  if (ABF16) ab = (const unsigned short*)Av + (size_t)g_rowc * K + s_oct * 8;
  else af = (const float*)Av + (size_t)g_rowc * K + s_oct * 8;

  // wave -> 32-row group (w&1), 64-col half (w>>1)
  const int rgrp = wave & 1;
  const int ch = wave >> 1;

  f32x4 acc[2][4];
#pragma unroll
  for (int r = 0; r < 2; ++r)
#pragma unroll
    for (int c = 0; c < 4; ++c) acc[r][c] = (f32x4){0.f, 0.f, 0.f, 0.f};

  union U8 { bf16x8 v; ushort4 u4[2]; unsigned short u[8]; uint4 q; };

  for (int ks = 0; ks < KSTEPS; ++ks) {
    // ---- stage A (64 x 32 -> bf16, padded) ----
    U8 aw;
    if (ABF16) {
      aw.q = *(const uint4*)(ab + ks * 32);
    } else {
      float4 f0 = *(const float4*)(af + ks * 32);
      float4 f1 = *(const float4*)(af + ks * 32 + 4);
      aw.u[0] = f2bf(f0.x); aw.u[1] = f2bf(f0.y);
      aw.u[2] = f2bf(f0.z); aw.u[3] = f2bf(f0.w);
      aw.u[4] = f2bf(f1.x); aw.u[5] = f2bf(f1.y);
      aw.u[6] = f2bf(f1.z); aw.u[7] = f2bf(f1.w);
    }
    *(uint4*)&Ah[s_row * ASTR + s_oct * 8] = aw.q;

    // ---- stage B via async global->LDS (flat 8 KB per plane, 2 KB/wave) ----
    {
      const unsigned short* sh = Bh + (size_t)ks * 4096 + wave * 1024;
      const unsigned short* sl = Bl + (size_t)ks * 4096 + wave * 1024;
      gl_lds16(sh + lane * 8, &Bhs[wave * 1024]);
      gl_lds16(sh + 512 + lane * 8, &Bhs[wave * 1024 + 512]);
      gl_lds16(sl + lane * 8, &Bls[wave * 1024]);
      gl_lds16(sl + 512 + lane * 8, &Bls[wave * 1024 + 512]);
    }
    __syncthreads();

    // ---- fragments + MFMA ----
    bf16x8 a0 = *(const bf16x8*)&Ah[(rgrp * 32 + (lane & 15)) * ASTR + (lane >> 4) * 8];
    bf16x8 a1 = *(const bf16x8*)&Ah[(rgrp * 32 + 16 + (lane & 15)) * ASTR + (lane >> 4) * 8];
#pragma unroll
    for (int c = 0; c < 4; ++c) {
      int ct = ch * 4 + c;
      bf16x8 bh = *(const bf16x8*)&Bhs[(ct * 64 + lane) * 8];
      bf16x8 bl = *(const bf16x8*)&Bls[(ct * 64 + lane) * 8];
      acc[0][c] = __builtin_amdgcn_mfma_f32_16x16x32_bf16(a0, bh, acc[0][c], 0, 0, 0);
      acc[0][c] = __builtin_amdgcn_mfma_f32_16x16x32_bf16(a0, bl, acc[0][c], 0, 0, 0);
      acc[1][c] = __builtin_amdgcn_mfma_f32_16x16x32_bf16(a1, bh, acc[1][c], 0, 0, 0);
      acc[1][c] = __builtin_amdgcn_mfma_f32_16x16x32_bf16(a1, bl, acc[1][c], 0, 0, 0);
    }
    __syncthreads();
  }

  // ---- epilogue: C/D layout col=lane&15, row=(lane>>4)*4+reg ----
  const int coln = lane & 15;
  const int rown = (lane >> 4) * 4;
#pragma unroll
  for (int c = 0; c < 4; ++c) {
    int colg = (ch * 4 + c) * 16 + coln;
    float bv = bias[colg];
#pragma unroll
    for (int r = 0; r < 2; ++r) {
#pragma unroll
      for (int reg = 0; reg < 4; ++reg) {
        int row = m0 + rgrp * 32 + r * 16 + rown + reg;
        if (row < M) {
          float v = acc[r][c][reg] + bv;
          if (RELU) v = fmaxf(v, 0.f);
          C[(size_t)row * DH + colg] = v;
        }
      }
    }
  }
}

// ---------------------------------------------------------------------------
// CSR build: degree histogram -> exclusive scan (3 kernels) -> cursor fill.
// ---------------------------------------------------------------------------
__global__ __launch_bounds__(256) void count_deg(const int* __restrict__ eidx,
                                                 int* __restrict__ cnt) {
  int e = blockIdx.x * 256 + threadIdx.x;
  if (e < N_EDGES) atomicAdd(&cnt[eidx[N_EDGES + e]], 1);
}

__global__ __launch_bounds__(256) void scan_block(const int* __restrict__ cnt,
                                                  int* __restrict__ rs,
                                                  int* __restrict__ partials) {
  int t = threadIdx.x;
  int i = blockIdx.x * 256 + t;
  int v = (i < N_NODES) ? cnt[i] : 0;
  __shared__ int s[256];
  s[t] = v;
  __syncthreads();
#pragma unroll
  for (int off = 1; off < 256; off <<= 1) {
    int add = (t >= off) ? s[t - off] : 0;
    __syncthreads();
    s[t] += add;
    __syncthreads();
  }
  if (i < N_NODES) rs[i] = s[t] - v;
  if (t == 255) partials[blockIdx.x] = s[255];
}

__global__ __launch_bounds__(256) void scan_partials(int* __restrict__ partials) {
  int t = threadIdx.x;
  int v = (t < SCAN_BLOCKS) ? partials[t] : 0;
  __shared__ int s[256];
  s[t] = v;
  __syncthreads();
#pragma unroll
  for (int off = 1; off < 256; off <<= 1) {
    int add = (t >= off) ? s[t - off] : 0;
    __syncthreads();
    s[t] += add;
    __syncthreads();
  }
  if (t < SCAN_BLOCKS) partials[t] = s[t] - v;
}

__global__ __launch_bounds__(256) void add_offsets(int* __restrict__ rs,
                                                   const int* __restrict__ partials) {
  int i = blockIdx.x * 256 + threadIdx.x;
  if (i < N_NODES) rs[i] += partials[blockIdx.x];
  if (i == 0) rs[N_NODES] = N_EDGES;
}

__global__ __launch_bounds__(256) void fill_csr(const int* __restrict__ eidx,
                                                const int* __restrict__ rs,
                                                int* __restrict__ cursor,
                                                int* __restrict__ esrc) {
  int e = blockIdx.x * 256 + threadIdx.x;
  if (e >= N_EDGES) return;
  int d = eidx[N_EDGES + e];
  int p = atomicAdd(&cursor[d], 1);
  esrc[rs[d] + p] = eidx[e];
}

// ---------------------------------------------------------------------------
// Aggregation gather (bf16 neighbors): yb[i] = bf16(x[i] + sum_j xb[src_j]).
// Wave per node; lane handles dims (2*lane, 2*lane+1) via one uint load/edge.
// Self term read exact from fp32 x. Output bf16-packed, coalesced.
// ---------------------------------------------------------------------------
__global__ __launch_bounds__(256) void gin_aggregate_bf16(
    const unsigned short* __restrict__ xb, const float* __restrict__ x,
    const int* __restrict__ rs, const int* __restrict__ esrc,
    unsigned* __restrict__ yb) {
  int node = blockIdx.x * 4 + (threadIdx.x >> 6);
  int lane = threadIdx.x & 63;
  if (node >= N_NODES) return;
  float2 acc = ((const float2*)x)[(size_t)node * 64 + lane];
  const unsigned* xb2 = (const unsigned*)xb;  // 2 bf16 per uint
  int beg = rs[node];
  int end = rs[node + 1];
  int j = beg;
  for (; j + 4 <= end; j += 4) {
    int s0 = esrc[j + 0];
    int s1 = esrc[j + 1];
    int s2 = esrc[j + 2];
    int s3 = esrc[j + 3];
    unsigned v0 = xb2[(size_t)s0 * 64 + lane];
    unsigned v1 = xb2[(size_t)s1 * 64 + lane];
    unsigned v2 = xb2[(size_t)s2 * 64 + lane];
    unsigned v3 = xb2[(size_t)s3 * 64 + lane];
    acc.x += (__uint_as_float(v0 << 16) + __uint_as_float(v1 << 16)) +
             (__uint_as_float(v2 << 16) + __uint_as_float(v3 << 16));
    acc.y += (__uint_as_float(v0 & 0xFFFF0000u) + __uint_as_float(v1 & 0xFFFF0000u)) +
             (__uint_as_float(v2 & 0xFFFF0000u) + __uint_as_float(v3 & 0xFFFF0000u));
  }
  for (; j < end; ++j) {
    unsigned v = xb2[(size_t)esrc[j] * 64 + lane];
    acc.x += __uint_as_float(v << 16);
    acc.y += __uint_as_float(v & 0xFFFF0000u);
  }
  yb[(size_t)node * 64 + lane] =
      (unsigned)f2bf(acc.x) | ((unsigned)f2bf(acc.y) << 16);
}

// ---------------------------------------------------------------------------
// Tail: z[i] = dot(x[i,:], tail_W) + tail_b, plus BN batch-stat partials.
// ---------------------------------------------------------------------------
__global__ __launch_bounds__(256) void tail_bn1(const float* __restrict__ x,
                                                const float* __restrict__ tw,
                                                const float* __restrict__ tb,
                                                float* __restrict__ z,
                                                float* __restrict__ red) {
  const int lane = threadIdx.x & 31;
  const int grp = threadIdx.x >> 5;
  float4 w = *(const float4*)(tw + lane * 4);
  float accS = 0.f, accQ = 0.f;
  for (int node = blockIdx.x * 8 + grp; node < N_NODES; node += gridDim.x * 8) {
    float4 v = *(const float4*)(x + (size_t)node * DH + lane * 4);
    float p = v.x * w.x + v.y * w.y + v.z * w.z + v.w * w.w;
#pragma unroll
    for (int m = 16; m; m >>= 1) p += __shfl_xor(p, m, 32);
    if (lane == 0) {
      float zv = p + tb[0];
      z[node] = zv;
      accS += zv;
      accQ += zv * zv;
    }
  }
  __shared__ float sS[256];
  __shared__ float sQ[256];
  sS[threadIdx.x] = accS;
  sQ[threadIdx.x] = accQ;
  __syncthreads();
  for (int s = 128; s; s >>= 1) {
    if (threadIdx.x < s) {
      sS[threadIdx.x] += sS[threadIdx.x + s];
      sQ[threadIdx.x] += sQ[threadIdx.x + s];
    }
    __syncthreads();
  }
  if (threadIdx.x == 0) {
    atomicAdd(&red[0], sS[0]);
    atomicAdd(&red[1], sQ[0]);
  }
}

__global__ __launch_bounds__(256) void bn2(const float* __restrict__ z,
                                           const float* __restrict__ red,
                                           const float* __restrict__ gamma,
                                           const float* __restrict__ beta,
                                           float* __restrict__ out) {
  int i = blockIdx.x * 256 + threadIdx.x;
  if (i >= N_NODES) return;
  float mu = red[0] * (1.0f / N_NODES);
  float var = red[1] * (1.0f / N_NODES) - mu * mu;
  out[i] = (z[i] - mu) * rsqrtf(var + BN_EPS) * gamma[0] + beta[0];
}

// ---------------------------------------------------------------------------
extern "C" void kernel_launch(void* const* d_in, const int* in_sizes, int n_in,
                              void* d_out, int out_size, void* d_ws, size_t ws_size,
                              hipStream_t stream) {
  const float* feature = (const float*)d_in[0];
  const int* eidx = (const int*)d_in[1];
  const float* head_W = (const float*)d_in[2];
  const float* head_b = (const float*)d_in[3];
  const float* gin_W1 = (const float*)d_in[4];
  const float* gin_b1 = (const float*)d_in[5];
  const float* lin_W1 = (const float*)d_in[6];
  const float* lin_b1 = (const float*)d_in[7];
  const float* gin_W2 = (const float*)d_in[8];
  const float* gin_b2 = (const float*)d_in[9];
  const float* lin_W2 = (const float*)d_in[10];
  const float* lin_b2 = (const float*)d_in[11];
  const float* tail_W = (const float*)d_in[12];
  const float* tail_b = (const float*)d_in[13];
  const float* bn_gamma = (const float*)d_in[14];
  const float* bn_beta = (const float*)d_in[15];

  float* X = (float*)d_ws;                       // N x 128 fp32
  float* H = X + (size_t)N_NODES * DH;           // N x 128 fp32
  float* z = H + (size_t)N_NODES * DH;           // N
  float* red = z + N_NODES;                      // 2 floats
  int* row_start = (int*)(red + 2);              // N+1
  int* cnt = row_start + (N_NODES + 1);          // N
  int* partials = cnt + N_NODES;                 // 256
  int* esrc = partials + 256;                    // E
  unsigned short* wp =
      (unsigned short*)(((uintptr_t)(esrc + N_EDGES) + 15) & ~(uintptr_t)15);
  unsigned short* hH = wp;            // head hi: 512*128
  unsigned short* hL = hH + 65536;    // head lo
  unsigned short* g1H = hL + 65536;   // 128*128 each below
  unsigned short* g1L = g1H + 16384;
  unsigned short* l1H = g1L + 16384;
  unsigned short* l1L = l1H + 16384;
  unsigned short* g2H = l1L + 16384;
  unsigned short* g2L = g2H + 16384;
  unsigned short* l2H = g2L + 16384;
  unsigned short* l2L = l2H + 16384;
  unsigned short* xb = l2L + 16384;              // bf16 mirror, N x 128
  unsigned* yb = (unsigned*)(xb + (size_t)N_NODES * DH);  // agg out bf16 N x 128

  const int gemm_grid = (N_NODES + 63) / 64;     // 782
  const int edge_grid = (N_EDGES + 255) / 256;
  const int agg_grid = (N_NODES + 3) / 4;
  const int cvt_grid = (N_NODES * DH / 4 + 255) / 256;

  // ---- weight pre-split (tiny) ----
  convert_W<<<(512 * 128 + 255) / 256, 256, 0, stream>>>(head_W, hH, hL, 512);
  convert_W<<<64, 256, 0, stream>>>(gin_W1, g1H, g1L, 128);
  convert_W<<<64, 256, 0, stream>>>(lin_W1, l1H, l1L, 128);
  convert_W<<<64, 256, 0, stream>>>(gin_W2, g2H, g2L, 128);
  convert_W<<<64, 256, 0, stream>>>(lin_W2, l2H, l2L, 128);

  // ---- CSR build (once; reused by both GIN layers) ----
  hipMemsetAsync(cnt, 0, N_NODES * sizeof(int), stream);
  hipMemsetAsync(red, 0, 2 * sizeof(float), stream);
  count_deg<<<edge_grid, 256, 0, stream>>>(eidx, cnt);
  scan_block<<<SCAN_BLOCKS, 256, 0, stream>>>(cnt, row_start, partials);
  scan_partials<<<1, 256, 0, stream>>>(partials);
  add_offsets<<<SCAN_BLOCKS, 256, 0, stream>>>(row_start, partials);
  hipMemsetAsync(cnt, 0, N_NODES * sizeof(int), stream);
  fill_csr<<<edge_grid, 256, 0, stream>>>(eidx, row_start, cnt, esrc);

  // ---- head: X = relu(feature @ head_W + head_b) ----
  gemm_tile<512, true, false><<<gemm_grid, 256, 0, stream>>>(
      feature, hH, hL, head_b, X, N_NODES);

  // ---- layer 1 ----
  to_bf16<<<cvt_grid, 256, 0, stream>>>(X, xb);
  gin_aggregate_bf16<<<agg_grid, 256, 0, stream>>>(xb, X, row_start, esrc, yb);
  gemm_tile<128, true, true><<<gemm_grid, 256, 0, stream>>>(
      yb, g1H, g1L, gin_b1, H, N_NODES);
  gemm_tile<128, false, false><<<gemm_grid, 256, 0, stream>>>(
      H, l1H, l1L, lin_b1, X, N_NODES);

  // ---- layer 2 ----
  to_bf16<<<cvt_grid, 256, 0, stream>>>(X, xb);
  gin_aggregate_bf16<<<agg_grid, 256, 0, stream>>>(xb, X, row_start, esrc, yb);
  gemm_tile<128, true, true><<<gemm_grid, 256, 0, stream>>>(
      yb, g2H, g2L, gin_b2, H, N_NODES);
  gemm_tile<128, false, false><<<gemm_grid, 256, 0, stream>>>(
      H, l2H, l2L, lin_b2, X, N_NODES);

  // ---- tail + batchnorm ----
  tail_bn1<<<256, 256, 0, stream>>>(X, tail_W, tail_b, z, red);
  bn2<<<(N_NODES + 255) / 256, 256, 0, stream>>>(z, red, bn_gamma, bn_beta, (float*)d_out);
}